// Round 1
// baseline (940.792 us; speedup 1.0000x reference)
//
#include <hip/hip_runtime.h>
#include <hip/hip_bf16.h>

#define DEV_INLINE __device__ __forceinline__

static constexpr int WAVE = 64;

DEV_INLINE float wave_max(float v) {
    #pragma unroll
    for (int o = 32; o > 0; o >>= 1) v = fmaxf(v, __shfl_xor(v, o));
    return v;
}
DEV_INLINE float wave_sum(float v) {
    #pragma unroll
    for (int o = 32; o > 0; o >>= 1) v += __shfl_xor(v, o);
    return v;
}
DEV_INLINE float leaky02(float x) { return x > 0.f ? x : 0.2f * x; }

// ---------------- gather: h0[n,64] = emb[x[n],64] ----------------
__global__ void gather_kernel(const float* __restrict__ emb, const int* __restrict__ x,
                              float* __restrict__ h, int n) {
    int idx = blockIdx.x * blockDim.x + threadIdx.x;
    if (idx >= n * 64) return;
    int node = idx >> 6, f = idx & 63;
    h[idx] = emb[x[node] * 64 + f];
}

// ---------------- CSR build ----------------
__global__ void count_kernel(const int* __restrict__ ei, int E, int* __restrict__ deg) {
    int i = blockIdx.x * blockDim.x + threadIdx.x;
    if (i >= E) return;
    atomicAdd(&deg[ei[E + i]], 1);
}

__global__ __launch_bounds__(1024)
void scan_kernel(const int* __restrict__ deg, int* __restrict__ off,
                 int* __restrict__ cursor, int n) {
    __shared__ int sums[1024];
    __shared__ int carryS;
    int tid = threadIdx.x;
    if (tid == 0) carryS = 0;
    __syncthreads();
    const int PER = 16;
    const int TILE = 1024 * PER;
    for (int base = 0; base < n; base += TILE) {
        int v[PER];
        int s = 0;
        int i0 = base + tid * PER;
        #pragma unroll
        for (int j = 0; j < PER; ++j) {
            int i = i0 + j;
            int x = (i < n) ? deg[i] : 0;
            v[j] = x; s += x;
        }
        sums[tid] = s;
        __syncthreads();
        for (int d = 1; d < 1024; d <<= 1) {
            int t = (tid >= d) ? sums[tid - d] : 0;
            __syncthreads();
            sums[tid] += t;
            __syncthreads();
        }
        int incl = sums[tid];
        int excl = incl - s;
        int total = sums[1023];
        int run = carryS + excl;
        #pragma unroll
        for (int j = 0; j < PER; ++j) {
            int i = i0 + j;
            if (i < n) { off[i] = run; cursor[i] = run; }
            run += v[j];
        }
        __syncthreads();
        if (tid == 0) carryS += total;
        __syncthreads();
    }
    if (tid == 0) off[n] = carryS;
}

__global__ void fill_kernel(const int* __restrict__ ei, int E,
                            int* __restrict__ cursor, int* __restrict__ ce) {
    int i = blockIdx.x * blockDim.x + threadIdx.x;
    if (i >= E) return;
    int d = ei[E + i];
    int pos = atomicAdd(&cursor[d], 1);
    ce[pos] = i;
}

// ---------------- watt[k] = sum_h We[k,h]*att[h], watt[8] = be.att ----------------
__global__ void watt_kernel(const float* __restrict__ We, const float* __restrict__ att,
                            const float* __restrict__ be, float* __restrict__ watt, int H) {
    int lane = threadIdx.x;
    for (int k = 0; k < 8; ++k) {
        float s = 0.f;
        for (int h = lane; h < H; h += WAVE) s += We[k * H + h] * att[h];
        s = wave_sum(s);
        if (lane == 0) watt[k] = s;
    }
    float s = 0.f;
    for (int h = lane; h < H; h += WAVE) s += be[h] * att[h];
    s = wave_sum(s);
    if (lane == 0) watt[8] = s;
}

// ---------------- escore[e] = ea[e,:].watt + watt[8] ----------------
__global__ void escore_kernel(const float* __restrict__ ea, const float* __restrict__ watt,
                              float* __restrict__ escore, int E) {
    int e = blockIdx.x * blockDim.x + threadIdx.x;
    if (e >= E) return;
    const float4* p = reinterpret_cast<const float4*>(ea + (size_t)e * 8);
    float4 a0 = p[0], a1 = p[1];
    float s = watt[8];
    s += a0.x * watt[0] + a0.y * watt[1] + a0.z * watt[2] + a0.w * watt[3];
    s += a1.x * watt[4] + a1.y * watt[5] + a1.z * watt[6] + a1.w * watt[7];
    escore[e] = s;
}

// ---------------- node linear: hWm = h@Wm+bm ; hWsb = h@Ws+bs ----------------
template <int DIN, int H>
__global__ void nodelin_kernel(const float* __restrict__ h,
                               const float* __restrict__ Wm, const float* __restrict__ bm,
                               const float* __restrict__ Ws, const float* __restrict__ bs,
                               float* __restrict__ hWm, float* __restrict__ hWsb, int n) {
    const int NPT = 4;
    int t = blockIdx.x * blockDim.x + threadIdx.x;
    int nGroups = (n + NPT - 1) / NPT;
    if (t >= nGroups * H) return;
    int g = t / H, f = t % H;
    int n0 = g * NPT;
    int nn = min(NPT, n - n0);
    float am[NPT], as[NPT];
    #pragma unroll
    for (int j = 0; j < NPT; ++j) { am[j] = bm[f]; as[j] = bs[f]; }
    for (int k = 0; k < DIN; ++k) {
        float wm = Wm[k * H + f];
        float ws = Ws[k * H + f];
        #pragma unroll
        for (int j = 0; j < NPT; ++j) {
            if (j < nn) {
                float hv = h[(size_t)(n0 + j) * DIN + k];
                am[j] += hv * wm;
                as[j] += hv * ws;
            }
        }
    }
    for (int j = 0; j < nn; ++j) {
        hWm[(size_t)(n0 + j) * H + f] = am[j];
        hWsb[(size_t)(n0 + j) * H + f] = as[j];
    }
}

// ---------------- nscore[n] = hWm[n,:].att ----------------
template <int H>
__global__ void nscore_kernel(const float* __restrict__ hWm, const float* __restrict__ att,
                              float* __restrict__ nscore, int n) {
    int gid = blockIdx.x * blockDim.x + threadIdx.x;
    int wid = gid >> 6, lane = gid & 63;
    if (wid >= n) return;
    float s = 0.f;
    #pragma unroll
    for (int r = 0; r < H / 64; ++r) {
        int hh = lane + r * 64;
        s += hWm[(size_t)wid * H + hh] * att[hh];
    }
    s = wave_sum(s);
    if (lane == 0) nscore[wid] = s;
}

// ---------------- aggregation: per-dst softmax + weighted mean + skip + relu ----------------
template <int H>
__global__ __launch_bounds__(64)
void agg_kernel(const int* __restrict__ csr_off, const int* __restrict__ ce,
                const int* __restrict__ ei, int E,
                const float* __restrict__ nscore, const float* __restrict__ escore,
                const float* __restrict__ ea,
                const float* __restrict__ We, const float* __restrict__ be,
                const float* __restrict__ hWm, const float* __restrict__ hWsb,
                float* __restrict__ hout, int n) {
    constexpr int R = H / 64;
    int node = blockIdx.x;
    if (node >= n) return;
    int lane = threadIdx.x;
    int off0 = csr_off[node];
    int deg = csr_off[node + 1] - off0;

    if (deg == 0) {
        #pragma unroll
        for (int r = 0; r < R; ++r) {
            float v = hWsb[(size_t)node * H + lane + r * 64];
            hout[(size_t)node * H + lane + r * 64] = fmaxf(v, 0.f);
        }
        return;
    }

    // register cache of We columns for this lane's features (+ be)
    float wreg[8][R], bereg[R];
    #pragma unroll
    for (int r = 0; r < R; ++r) {
        bereg[r] = be[lane + r * 64];
        #pragma unroll
        for (int k = 0; k < 8; ++k) wreg[k][r] = We[k * H + lane + r * 64];
    }

    // pass 1: max of leaky_relu scores
    float mx = -1e30f;
    for (int base = 0; base < deg; base += WAVE) {
        int i = base + lane;
        if (i < deg) {
            int e = ce[off0 + i];
            float a = leaky02(nscore[ei[e]] + escore[e]);
            mx = fmaxf(mx, a);
        }
    }
    mx = wave_max(mx);

    // pass 2: sum of exp
    float ssum = 0.f;
    for (int base = 0; base < deg; base += WAVE) {
        int i = base + lane;
        if (i < deg) {
            int e = ce[off0 + i];
            float a = leaky02(nscore[ei[e]] + escore[e]);
            ssum += expf(a - mx);
        }
    }
    ssum = wave_sum(ssum);
    float invd = 1.f / (ssum + 1e-16f);

    // pass 3: weighted accumulate of (hWm[src] + ea@We + be)
    float acc[R];
    #pragma unroll
    for (int r = 0; r < R; ++r) acc[r] = 0.f;

    for (int base = 0; base < deg; base += WAVE) {
        int cnt = min(WAVE, deg - base);
        int i = base + lane;
        int e = 0, s_ = 0;
        float cf = 0.f;
        if (i < deg) {
            e = ce[off0 + i];
            s_ = ei[e];
            float a = leaky02(nscore[s_] + escore[e]);
            cf = expf(a - mx) * invd;
        }
        for (int j = 0; j < cnt; ++j) {
            int ej = __shfl(e, j);
            int sj = __shfl(s_, j);
            float cj = __shfl(cf, j);
            const float4* p = reinterpret_cast<const float4*>(ea + (size_t)ej * 8);
            float4 a0 = p[0], a1 = p[1];
            #pragma unroll
            for (int r = 0; r < R; ++r) {
                float ew = bereg[r];
                ew += a0.x * wreg[0][r] + a0.y * wreg[1][r] + a0.z * wreg[2][r] + a0.w * wreg[3][r];
                ew += a1.x * wreg[4][r] + a1.y * wreg[5][r] + a1.z * wreg[6][r] + a1.w * wreg[7][r];
                float x = hWm[(size_t)sj * H + lane + r * 64];
                acc[r] += cj * (x + ew);
            }
        }
    }

    float invdeg = 1.f / (float)deg;
    #pragma unroll
    for (int r = 0; r < R; ++r) {
        float v = acc[r] * invdeg + hWsb[(size_t)node * H + lane + r * 64];
        hout[(size_t)node * H + lane + r * 64] = fmaxf(v, 0.f);
    }
}

// ---------------- pooling ----------------
__global__ void pool_cnt_kernel(const int* __restrict__ batchh, int* __restrict__ gcnt, int n) {
    int i = blockIdx.x * blockDim.x + threadIdx.x;
    if (i >= n) return;
    atomicAdd(&gcnt[batchh[i]], 1);
}

__global__ __launch_bounds__(128)
void pool_sum_kernel(const float* __restrict__ h, const int* __restrict__ batchh,
                     float* __restrict__ gsum, int n) {
    int f = threadIdx.x;  // 0..127
    int chunk = (n + gridDim.x - 1) / gridDim.x;
    int start = blockIdx.x * chunk;
    int end = min(n, start + chunk);
    if (start >= end) return;
    float acc = 0.f;
    int cur = batchh[start];
    for (int node = start; node < end; ++node) {
        int b = batchh[node];
        if (b != cur) {
            atomicAdd(&gsum[cur * 128 + f], acc);
            acc = 0.f;
            cur = b;
        }
        acc += h[(size_t)node * 128 + f];
    }
    atomicAdd(&gsum[cur * 128 + f], acc);
}

// ---------------- classifier ----------------
__global__ __launch_bounds__(128)
void classifier_kernel(const float* __restrict__ gsum, const int* __restrict__ gcnt,
                       const float* __restrict__ Wc1, const float* __restrict__ bc1,
                       const float* __restrict__ Wc2, const float* __restrict__ bc2,
                       float* __restrict__ out) {
    int b = blockIdx.x;
    int f = threadIdx.x;
    __shared__ float gm[128];
    __shared__ float t1[128];
    float c = (float)max(gcnt[b], 1);
    gm[f] = gsum[b * 128 + f] / c;
    __syncthreads();
    float acc = bc1[f];
    for (int k = 0; k < 128; ++k) acc += gm[k] * Wc1[k * 128 + f];
    t1[f] = fmaxf(acc, 0.f);
    __syncthreads();
    if (f < 4) {
        float o = bc2[f];
        for (int k = 0; k < 128; ++k) o += t1[k] * Wc2[k * 4 + f];
        out[b * 4 + f] = o;
    }
}

extern "C" void kernel_launch(void* const* d_in, const int* in_sizes, int n_in,
                              void* d_out, int out_size, void* d_ws, size_t ws_size,
                              hipStream_t stream) {
    const int* x      = (const int*)d_in[0];
    const int* ei     = (const int*)d_in[1];
    const float* ea   = (const float*)d_in[2];
    const int* batchh = (const int*)d_in[3];
    const float* emb  = (const float*)d_in[4];
    const float* Wm0 = (const float*)d_in[5];  const float* bm0 = (const float*)d_in[6];
    const float* We0 = (const float*)d_in[7];  const float* be0 = (const float*)d_in[8];
    const float* att0 = (const float*)d_in[9];
    const float* Ws0 = (const float*)d_in[10]; const float* bs0 = (const float*)d_in[11];
    const float* Wm1 = (const float*)d_in[12]; const float* bm1 = (const float*)d_in[13];
    const float* We1 = (const float*)d_in[14]; const float* be1 = (const float*)d_in[15];
    const float* att1 = (const float*)d_in[16];
    const float* Ws1 = (const float*)d_in[17]; const float* bs1 = (const float*)d_in[18];
    const float* Wc1 = (const float*)d_in[19]; const float* bc1 = (const float*)d_in[20];
    const float* Wc2 = (const float*)d_in[21]; const float* bc2 = (const float*)d_in[22];

    const int N = in_sizes[0];
    const int E = in_sizes[1] / 2;
    const int G = 64;
    const int H2 = 128;

    // workspace carve-out (256B aligned)
    char* w = (char*)d_ws;
    auto alloc = [&](size_t bytes) -> void* {
        void* p = (void*)w;
        w += (bytes + 255) & ~(size_t)255;
        return p;
    };
    float* hbuf   = (float*)alloc((size_t)N * 128 * 4);
    float* hWm    = (float*)alloc((size_t)N * 128 * 4);
    float* hWsb   = (float*)alloc((size_t)N * 128 * 4);
    float* nscore = (float*)alloc((size_t)N * 4);
    float* escore = (float*)alloc((size_t)E * 4);
    int* degcnt   = (int*)alloc((size_t)N * 4);
    int* csroff   = (int*)alloc((size_t)(N + 1) * 4);
    int* cursor   = (int*)alloc((size_t)N * 4);
    int* ce       = (int*)alloc((size_t)E * 4);
    float* watt   = (float*)alloc(16 * 4);
    float* gsum   = (float*)alloc((size_t)G * H2 * 4);
    int* gcnt     = (int*)alloc((size_t)G * 4);

    auto cdiv = [](int a, int b) { return (a + b - 1) / b; };

    hipMemsetAsync(degcnt, 0, (size_t)N * 4, stream);
    hipMemsetAsync(gsum, 0, (size_t)G * H2 * 4, stream);
    hipMemsetAsync(gcnt, 0, (size_t)G * 4, stream);

    // h0 = emb[x]
    gather_kernel<<<cdiv(N * 64, 256), 256, 0, stream>>>(emb, x, hbuf, N);

    // CSR by dst
    count_kernel<<<cdiv(E, 256), 256, 0, stream>>>(ei, E, degcnt);
    scan_kernel<<<1, 1024, 0, stream>>>(degcnt, csroff, cursor, N);
    fill_kernel<<<cdiv(E, 256), 256, 0, stream>>>(ei, E, cursor, ce);

    // ---- layer 0: 64 -> 64 ----
    watt_kernel<<<1, 64, 0, stream>>>(We0, att0, be0, watt, 64);
    escore_kernel<<<cdiv(E, 256), 256, 0, stream>>>(ea, watt, escore, E);
    nodelin_kernel<64, 64><<<cdiv(cdiv(N, 4) * 64, 256), 256, 0, stream>>>(
        hbuf, Wm0, bm0, Ws0, bs0, hWm, hWsb, N);
    nscore_kernel<64><<<cdiv(N, 4), 256, 0, stream>>>(hWm, att0, nscore, N);
    agg_kernel<64><<<N, 64, 0, stream>>>(csroff, ce, ei, E, nscore, escore, ea,
                                         We0, be0, hWm, hWsb, hbuf, N);

    // ---- layer 1: 64 -> 128 ----
    watt_kernel<<<1, 64, 0, stream>>>(We1, att1, be1, watt, 128);
    escore_kernel<<<cdiv(E, 256), 256, 0, stream>>>(ea, watt, escore, E);
    nodelin_kernel<64, 128><<<cdiv(cdiv(N, 4) * 128, 256), 256, 0, stream>>>(
        hbuf, Wm1, bm1, Ws1, bs1, hWm, hWsb, N);
    nscore_kernel<128><<<cdiv(N, 4), 256, 0, stream>>>(hWm, att1, nscore, N);
    agg_kernel<128><<<N, 64, 0, stream>>>(csroff, ce, ei, E, nscore, escore, ea,
                                          We1, be1, hWm, hWsb, hbuf, N);

    // ---- global mean pool + classifier ----
    pool_cnt_kernel<<<cdiv(N, 256), 256, 0, stream>>>(batchh, gcnt, N);
    pool_sum_kernel<<<512, 128, 0, stream>>>(hbuf, batchh, gsum, N);
    classifier_kernel<<<G, 128, 0, stream>>>(gsum, gcnt, Wc1, bc1, Wc2, bc2, (float*)d_out);
}

// Round 2
// 714.673 us; speedup vs baseline: 1.3164x; 1.3164x over previous
//
#include <hip/hip_runtime.h>
#include <hip/hip_bf16.h>

#define DEV_INLINE __device__ __forceinline__

static constexpr int WAVE = 64;

DEV_INLINE float wave_max(float v) {
    #pragma unroll
    for (int o = 32; o > 0; o >>= 1) v = fmaxf(v, __shfl_xor(v, o));
    return v;
}
DEV_INLINE float wave_sum(float v) {
    #pragma unroll
    for (int o = 32; o > 0; o >>= 1) v += __shfl_xor(v, o);
    return v;
}
DEV_INLINE float leaky02(float x) { return x > 0.f ? x : 0.2f * x; }

// ---------------- gather: h0[n,64] = emb[x[n],64] ----------------
__global__ void gather_kernel(const float* __restrict__ emb, const int* __restrict__ x,
                              float* __restrict__ h, int n) {
    int idx = blockIdx.x * blockDim.x + threadIdx.x;
    if (idx >= n * 64) return;
    int node = idx >> 6, f = idx & 63;
    h[idx] = emb[x[node] * 64 + f];
}

// ---------------- CSR build ----------------
__global__ void count_kernel(const int* __restrict__ ei, int E, int* __restrict__ deg) {
    int i = blockIdx.x * blockDim.x + threadIdx.x;
    if (i >= E) return;
    atomicAdd(&deg[ei[E + i]], 1);
}

__global__ __launch_bounds__(1024)
void scan_kernel(const int* __restrict__ deg, int* __restrict__ off,
                 int* __restrict__ cursor, int n) {
    __shared__ int sums[1024];
    __shared__ int carryS;
    int tid = threadIdx.x;
    if (tid == 0) carryS = 0;
    __syncthreads();
    const int PER = 16;
    const int TILE = 1024 * PER;
    for (int base = 0; base < n; base += TILE) {
        int v[PER];
        int s = 0;
        int i0 = base + tid * PER;
        #pragma unroll
        for (int j = 0; j < PER; ++j) {
            int i = i0 + j;
            int x = (i < n) ? deg[i] : 0;
            v[j] = x; s += x;
        }
        sums[tid] = s;
        __syncthreads();
        for (int d = 1; d < 1024; d <<= 1) {
            int t = (tid >= d) ? sums[tid - d] : 0;
            __syncthreads();
            sums[tid] += t;
            __syncthreads();
        }
        int incl = sums[tid];
        int excl = incl - s;
        int total = sums[1023];
        int run = carryS + excl;
        #pragma unroll
        for (int j = 0; j < PER; ++j) {
            int i = i0 + j;
            if (i < n) { off[i] = run; cursor[i] = run; }
            run += v[j];
        }
        __syncthreads();
        if (tid == 0) carryS += total;
        __syncthreads();
    }
    if (tid == 0) off[n] = carryS;
}

__global__ void fill_kernel(const int* __restrict__ ei, int E,
                            int* __restrict__ cursor, int* __restrict__ ce) {
    int i = blockIdx.x * blockDim.x + threadIdx.x;
    if (i >= E) return;
    int d = ei[E + i];
    int pos = atomicAdd(&cursor[d], 1);
    ce[pos] = i;
}

// ---------------- watt[k] = sum_h We[k,h]*att[h], watt[8] = be.att ----------------
__global__ void watt_kernel(const float* __restrict__ We, const float* __restrict__ att,
                            const float* __restrict__ be, float* __restrict__ watt, int H) {
    int lane = threadIdx.x;
    for (int k = 0; k < 8; ++k) {
        float s = 0.f;
        for (int h = lane; h < H; h += WAVE) s += We[k * H + h] * att[h];
        s = wave_sum(s);
        if (lane == 0) watt[k] = s;
    }
    float s = 0.f;
    for (int h = lane; h < H; h += WAVE) s += be[h] * att[h];
    s = wave_sum(s);
    if (lane == 0) watt[8] = s;
}

// ---------------- escore[e] = ea[e,:].watt + watt[8] ----------------
__global__ void escore_kernel(const float* __restrict__ ea, const float* __restrict__ watt,
                              float* __restrict__ escore, int E) {
    int e = blockIdx.x * blockDim.x + threadIdx.x;
    if (e >= E) return;
    const float4* p = reinterpret_cast<const float4*>(ea + (size_t)e * 8);
    float4 a0 = p[0], a1 = p[1];
    float s = watt[8];
    s += a0.x * watt[0] + a0.y * watt[1] + a0.z * watt[2] + a0.w * watt[3];
    s += a1.x * watt[4] + a1.y * watt[5] + a1.z * watt[6] + a1.w * watt[7];
    escore[e] = s;
}

// ---------------- node linear: hWm = h@Wm+bm ; hWsb = h@Ws+bs ----------------
template <int DIN, int H>
__global__ void nodelin_kernel(const float* __restrict__ h,
                               const float* __restrict__ Wm, const float* __restrict__ bm,
                               const float* __restrict__ Ws, const float* __restrict__ bs,
                               float* __restrict__ hWm, float* __restrict__ hWsb, int n) {
    const int NPT = 4;
    int t = blockIdx.x * blockDim.x + threadIdx.x;
    int nGroups = (n + NPT - 1) / NPT;
    if (t >= nGroups * H) return;
    int g = t / H, f = t % H;
    int n0 = g * NPT;
    int nn = min(NPT, n - n0);
    float am[NPT], as[NPT];
    #pragma unroll
    for (int j = 0; j < NPT; ++j) { am[j] = bm[f]; as[j] = bs[f]; }
    for (int k = 0; k < DIN; ++k) {
        float wm = Wm[k * H + f];
        float ws = Ws[k * H + f];
        #pragma unroll
        for (int j = 0; j < NPT; ++j) {
            if (j < nn) {
                float hv = h[(size_t)(n0 + j) * DIN + k];
                am[j] += hv * wm;
                as[j] += hv * ws;
            }
        }
    }
    for (int j = 0; j < nn; ++j) {
        hWm[(size_t)(n0 + j) * H + f] = am[j];
        hWsb[(size_t)(n0 + j) * H + f] = as[j];
    }
}

// ---------------- nscore[n] = hWm[n,:].att ----------------
template <int H>
__global__ void nscore_kernel(const float* __restrict__ hWm, const float* __restrict__ att,
                              float* __restrict__ nscore, int n) {
    int gid = blockIdx.x * blockDim.x + threadIdx.x;
    int wid = gid >> 6, lane = gid & 63;
    if (wid >= n) return;
    float s = 0.f;
    #pragma unroll
    for (int r = 0; r < H / 64; ++r) {
        int hh = lane + r * 64;
        s += hWm[(size_t)wid * H + hh] * att[hh];
    }
    s = wave_sum(s);
    if (lane == 0) nscore[wid] = s;
}

// ---------------- aggregation: per-dst softmax + weighted mean + skip + relu ----------------
template <int H>
__global__ __launch_bounds__(64)
void agg_kernel(const int* __restrict__ csr_off, const int* __restrict__ ce,
                const int* __restrict__ ei, int E,
                const float* __restrict__ nscore, const float* __restrict__ escore,
                const float* __restrict__ ea,
                const float* __restrict__ We, const float* __restrict__ be,
                const float* __restrict__ hWm, const float* __restrict__ hWsb,
                float* __restrict__ hout, int n) {
    constexpr int R = H / 64;
    int node = blockIdx.x;
    if (node >= n) return;
    int lane = threadIdx.x;
    int off0 = csr_off[node];
    int deg = csr_off[node + 1] - off0;

    if (deg == 0) {
        #pragma unroll
        for (int r = 0; r < R; ++r) {
            float v = hWsb[(size_t)node * H + lane + r * 64];
            hout[(size_t)node * H + lane + r * 64] = fmaxf(v, 0.f);
        }
        return;
    }

    // register cache of We columns for this lane's features (+ be)
    float wreg[8][R], bereg[R];
    #pragma unroll
    for (int r = 0; r < R; ++r) {
        bereg[r] = be[lane + r * 64];
        #pragma unroll
        for (int k = 0; k < 8; ++k) wreg[k][r] = We[k * H + lane + r * 64];
    }

    // pass 1: max of leaky_relu scores
    float mx = -1e30f;
    for (int base = 0; base < deg; base += WAVE) {
        int i = base + lane;
        if (i < deg) {
            int e = ce[off0 + i];
            float a = leaky02(nscore[ei[e]] + escore[e]);
            mx = fmaxf(mx, a);
        }
    }
    mx = wave_max(mx);

    // pass 2: sum of exp
    float ssum = 0.f;
    for (int base = 0; base < deg; base += WAVE) {
        int i = base + lane;
        if (i < deg) {
            int e = ce[off0 + i];
            float a = leaky02(nscore[ei[e]] + escore[e]);
            ssum += expf(a - mx);
        }
    }
    ssum = wave_sum(ssum);
    float invd = 1.f / (ssum + 1e-16f);

    // pass 3: weighted accumulate of (hWm[src] + ea@We + be)
    float acc[R];
    #pragma unroll
    for (int r = 0; r < R; ++r) acc[r] = 0.f;

    for (int base = 0; base < deg; base += WAVE) {
        int cnt = min(WAVE, deg - base);
        int i = base + lane;
        int e = 0, s_ = 0;
        float cf = 0.f;
        if (i < deg) {
            e = ce[off0 + i];
            s_ = ei[e];
            float a = leaky02(nscore[s_] + escore[e]);
            cf = expf(a - mx) * invd;
        }
        for (int j = 0; j < cnt; ++j) {
            int ej = __shfl(e, j);
            int sj = __shfl(s_, j);
            float cj = __shfl(cf, j);
            const float4* p = reinterpret_cast<const float4*>(ea + (size_t)ej * 8);
            float4 a0 = p[0], a1 = p[1];
            #pragma unroll
            for (int r = 0; r < R; ++r) {
                float ew = bereg[r];
                ew += a0.x * wreg[0][r] + a0.y * wreg[1][r] + a0.z * wreg[2][r] + a0.w * wreg[3][r];
                ew += a1.x * wreg[4][r] + a1.y * wreg[5][r] + a1.z * wreg[6][r] + a1.w * wreg[7][r];
                float x = hWm[(size_t)sj * H + lane + r * 64];
                acc[r] += cj * (x + ew);
            }
        }
    }

    float invdeg = 1.f / (float)deg;
    #pragma unroll
    for (int r = 0; r < R; ++r) {
        float v = acc[r] * invdeg + hWsb[(size_t)node * H + lane + r * 64];
        hout[(size_t)node * H + lane + r * 64] = fmaxf(v, 0.f);
    }
}

// ---------------- graph counts via binary search on sorted batchh ----------------
// batchh is sorted ascending; gcnt[b] = lower_bound(b+1) - lower_bound(b).
// Replaces the 235us atomic-contention pool_cnt_kernel with ~2us of cached loads.
__global__ void graph_cnt_kernel(const int* __restrict__ batchh, int* __restrict__ gcnt,
                                 int n, int G) {
    int b = blockIdx.x * blockDim.x + threadIdx.x;
    if (b >= G) return;
    auto lb = [&](int key) {
        int lo = 0, hi = n;
        while (lo < hi) {
            int mid = (lo + hi) >> 1;
            if (batchh[mid] < key) lo = mid + 1; else hi = mid;
        }
        return lo;
    };
    gcnt[b] = lb(b + 1) - lb(b);
}

__global__ __launch_bounds__(128)
void pool_sum_kernel(const float* __restrict__ h, const int* __restrict__ batchh,
                     float* __restrict__ gsum, int n) {
    int f = threadIdx.x;  // 0..127
    int chunk = (n + gridDim.x - 1) / gridDim.x;
    int start = blockIdx.x * chunk;
    int end = min(n, start + chunk);
    if (start >= end) return;
    float acc = 0.f;
    int cur = batchh[start];
    for (int node = start; node < end; ++node) {
        int b = batchh[node];
        if (b != cur) {
            atomicAdd(&gsum[cur * 128 + f], acc);
            acc = 0.f;
            cur = b;
        }
        acc += h[(size_t)node * 128 + f];
    }
    atomicAdd(&gsum[cur * 128 + f], acc);
}

// ---------------- classifier ----------------
__global__ __launch_bounds__(128)
void classifier_kernel(const float* __restrict__ gsum, const int* __restrict__ gcnt,
                       const float* __restrict__ Wc1, const float* __restrict__ bc1,
                       const float* __restrict__ Wc2, const float* __restrict__ bc2,
                       float* __restrict__ out) {
    int b = blockIdx.x;
    int f = threadIdx.x;
    __shared__ float gm[128];
    __shared__ float t1[128];
    float c = (float)max(gcnt[b], 1);
    gm[f] = gsum[b * 128 + f] / c;
    __syncthreads();
    float acc = bc1[f];
    for (int k = 0; k < 128; ++k) acc += gm[k] * Wc1[k * 128 + f];
    t1[f] = fmaxf(acc, 0.f);
    __syncthreads();
    if (f < 4) {
        float o = bc2[f];
        for (int k = 0; k < 128; ++k) o += t1[k] * Wc2[k * 4 + f];
        out[b * 4 + f] = o;
    }
}

extern "C" void kernel_launch(void* const* d_in, const int* in_sizes, int n_in,
                              void* d_out, int out_size, void* d_ws, size_t ws_size,
                              hipStream_t stream) {
    const int* x      = (const int*)d_in[0];
    const int* ei     = (const int*)d_in[1];
    const float* ea   = (const float*)d_in[2];
    const int* batchh = (const int*)d_in[3];
    const float* emb  = (const float*)d_in[4];
    const float* Wm0 = (const float*)d_in[5];  const float* bm0 = (const float*)d_in[6];
    const float* We0 = (const float*)d_in[7];  const float* be0 = (const float*)d_in[8];
    const float* att0 = (const float*)d_in[9];
    const float* Ws0 = (const float*)d_in[10]; const float* bs0 = (const float*)d_in[11];
    const float* Wm1 = (const float*)d_in[12]; const float* bm1 = (const float*)d_in[13];
    const float* We1 = (const float*)d_in[14]; const float* be1 = (const float*)d_in[15];
    const float* att1 = (const float*)d_in[16];
    const float* Ws1 = (const float*)d_in[17]; const float* bs1 = (const float*)d_in[18];
    const float* Wc1 = (const float*)d_in[19]; const float* bc1 = (const float*)d_in[20];
    const float* Wc2 = (const float*)d_in[21]; const float* bc2 = (const float*)d_in[22];

    const int N = in_sizes[0];
    const int E = in_sizes[1] / 2;
    const int G = 64;
    const int H2 = 128;

    // workspace carve-out (256B aligned)
    char* w = (char*)d_ws;
    auto alloc = [&](size_t bytes) -> void* {
        void* p = (void*)w;
        w += (bytes + 255) & ~(size_t)255;
        return p;
    };
    float* hbuf   = (float*)alloc((size_t)N * 128 * 4);
    float* hWm    = (float*)alloc((size_t)N * 128 * 4);
    float* hWsb   = (float*)alloc((size_t)N * 128 * 4);
    float* nscore = (float*)alloc((size_t)N * 4);
    float* escore = (float*)alloc((size_t)E * 4);
    int* degcnt   = (int*)alloc((size_t)N * 4);
    int* csroff   = (int*)alloc((size_t)(N + 1) * 4);
    int* cursor   = (int*)alloc((size_t)N * 4);
    int* ce       = (int*)alloc((size_t)E * 4);
    float* watt   = (float*)alloc(16 * 4);
    float* gsum   = (float*)alloc((size_t)G * H2 * 4);
    int* gcnt     = (int*)alloc((size_t)G * 4);

    auto cdiv = [](int a, int b) { return (a + b - 1) / b; };

    hipMemsetAsync(degcnt, 0, (size_t)N * 4, stream);
    hipMemsetAsync(gsum, 0, (size_t)G * H2 * 4, stream);

    // h0 = emb[x]
    gather_kernel<<<cdiv(N * 64, 256), 256, 0, stream>>>(emb, x, hbuf, N);

    // CSR by dst
    count_kernel<<<cdiv(E, 256), 256, 0, stream>>>(ei, E, degcnt);
    scan_kernel<<<1, 1024, 0, stream>>>(degcnt, csroff, cursor, N);
    fill_kernel<<<cdiv(E, 256), 256, 0, stream>>>(ei, E, cursor, ce);

    // ---- layer 0: 64 -> 64 ----
    watt_kernel<<<1, 64, 0, stream>>>(We0, att0, be0, watt, 64);
    escore_kernel<<<cdiv(E, 256), 256, 0, stream>>>(ea, watt, escore, E);
    nodelin_kernel<64, 64><<<cdiv(cdiv(N, 4) * 64, 256), 256, 0, stream>>>(
        hbuf, Wm0, bm0, Ws0, bs0, hWm, hWsb, N);
    nscore_kernel<64><<<cdiv(N, 4), 256, 0, stream>>>(hWm, att0, nscore, N);
    agg_kernel<64><<<N, 64, 0, stream>>>(csroff, ce, ei, E, nscore, escore, ea,
                                         We0, be0, hWm, hWsb, hbuf, N);

    // ---- layer 1: 64 -> 128 ----
    watt_kernel<<<1, 64, 0, stream>>>(We1, att1, be1, watt, 128);
    escore_kernel<<<cdiv(E, 256), 256, 0, stream>>>(ea, watt, escore, E);
    nodelin_kernel<64, 128><<<cdiv(cdiv(N, 4) * 128, 256), 256, 0, stream>>>(
        hbuf, Wm1, bm1, Ws1, bs1, hWm, hWsb, N);
    nscore_kernel<128><<<cdiv(N, 4), 256, 0, stream>>>(hWm, att1, nscore, N);
    agg_kernel<128><<<N, 64, 0, stream>>>(csroff, ce, ei, E, nscore, escore, ea,
                                          We1, be1, hWm, hWsb, hbuf, N);

    // ---- global mean pool + classifier ----
    graph_cnt_kernel<<<1, 64, 0, stream>>>(batchh, gcnt, N, G);
    pool_sum_kernel<<<512, 128, 0, stream>>>(hbuf, batchh, gsum, N);
    classifier_kernel<<<G, 128, 0, stream>>>(gsum, gcnt, Wc1, bc1, Wc2, bc2, (float*)d_out);
}

// Round 3
// 578.559 us; speedup vs baseline: 1.6261x; 1.2353x over previous
//
#include <hip/hip_runtime.h>
#include <hip/hip_bf16.h>

#define DEV_INLINE __device__ __forceinline__

static constexpr int WAVE = 64;

DEV_INLINE float wave_max(float v) {
    #pragma unroll
    for (int o = 32; o > 0; o >>= 1) v = fmaxf(v, __shfl_xor(v, o));
    return v;
}
DEV_INLINE float wave_sum(float v) {
    #pragma unroll
    for (int o = 32; o > 0; o >>= 1) v += __shfl_xor(v, o);
    return v;
}
DEV_INLINE float leaky02(float x) { return x > 0.f ? x : 0.2f * x; }

// ---------------- CSR build ----------------
__global__ void count_kernel(const int* __restrict__ ei, int E, int* __restrict__ deg) {
    int i = blockIdx.x * blockDim.x + threadIdx.x;
    if (i >= E) return;
    atomicAdd(&deg[ei[E + i]], 1);
}

__global__ __launch_bounds__(1024)
void scan_kernel(const int* __restrict__ deg, int* __restrict__ off,
                 int* __restrict__ cursor, int n) {
    __shared__ int sums[1024];
    __shared__ int carryS;
    int tid = threadIdx.x;
    if (tid == 0) carryS = 0;
    __syncthreads();
    const int PER = 16;
    const int TILE = 1024 * PER;
    for (int base = 0; base < n; base += TILE) {
        int v[PER];
        int s = 0;
        int i0 = base + tid * PER;
        #pragma unroll
        for (int j = 0; j < PER; ++j) {
            int i = i0 + j;
            int x = (i < n) ? deg[i] : 0;
            v[j] = x; s += x;
        }
        sums[tid] = s;
        __syncthreads();
        for (int d = 1; d < 1024; d <<= 1) {
            int t = (tid >= d) ? sums[tid - d] : 0;
            __syncthreads();
            sums[tid] += t;
            __syncthreads();
        }
        int incl = sums[tid];
        int excl = incl - s;
        int total = sums[1023];
        int run = carryS + excl;
        #pragma unroll
        for (int j = 0; j < PER; ++j) {
            int i = i0 + j;
            if (i < n) { off[i] = run; cursor[i] = run; }
            run += v[j];
        }
        __syncthreads();
        if (tid == 0) carryS += total;
        __syncthreads();
    }
    if (tid == 0) off[n] = carryS;
}

__global__ void fill_kernel(const int* __restrict__ ei, int E,
                            int* __restrict__ cursor, int* __restrict__ ce) {
    int i = blockIdx.x * blockDim.x + threadIdx.x;
    if (i >= E) return;
    int d = ei[E + i];
    int pos = atomicAdd(&cursor[d], 1);
    ce[pos] = i;
}

// ---------------- watt[k] = sum_h We[k,h]*att[h], watt[8] = be.att ----------------
__global__ void watt_kernel(const float* __restrict__ We, const float* __restrict__ att,
                            const float* __restrict__ be, float* __restrict__ watt, int H) {
    int lane = threadIdx.x;
    for (int k = 0; k < 8; ++k) {
        float s = 0.f;
        for (int h = lane; h < H; h += WAVE) s += We[k * H + h] * att[h];
        s = wave_sum(s);
        if (lane == 0) watt[k] = s;
    }
    float s = 0.f;
    for (int h = lane; h < H; h += WAVE) s += be[h] * att[h];
    s = wave_sum(s);
    if (lane == 0) watt[8] = s;
}

// ---------------- escore[e] = ea[e,:].watt + watt[8] ----------------
__global__ void escore_kernel(const float* __restrict__ ea, const float* __restrict__ watt,
                              float* __restrict__ escore, int E) {
    int e = blockIdx.x * blockDim.x + threadIdx.x;
    if (e >= E) return;
    const float4* p = reinterpret_cast<const float4*>(ea + (size_t)e * 8);
    float4 a0 = p[0], a1 = p[1];
    float s = watt[8];
    s += a0.x * watt[0] + a0.y * watt[1] + a0.z * watt[2] + a0.w * watt[3];
    s += a1.x * watt[4] + a1.y * watt[5] + a1.z * watt[6] + a1.w * watt[7];
    escore[e] = s;
}

// ---------------- node linear (LDS-tiled register-blocked GEMM) ----------------
// hWm = h@Wm+bm ; hWsb = h@Ws+bs. Optional xidx fuses the emb[x] gather.
// Thread layout: F4=H/4 feature-quads; NC=256/F4 concurrent nodes; NPT nodes/thread.
template <int H, int NB>
__global__ __launch_bounds__(256)
void nodelin_kernel(const float* __restrict__ h, const int* __restrict__ xidx,
                    const float* __restrict__ Wm, const float* __restrict__ bm,
                    const float* __restrict__ Ws, const float* __restrict__ bs,
                    float* __restrict__ hWm, float* __restrict__ hWsb, int n) {
    constexpr int F4  = H / 4;
    constexpr int NC  = 256 / F4;
    constexpr int NPT = NB / NC;
    constexpr int LDW = 68;  // padded row stride (floats): 68%32=4 -> no bank conflict across rows
    __shared__ float sh[NB][LDW];
    int n0 = blockIdx.x * NB;
    int tid = threadIdx.x;

    // stage h tile (float4 coalesced)
    for (int i = tid; i < NB * 16; i += 256) {
        int node = i >> 4, q = i & 15;
        int row = n0 + node;
        float4 v = make_float4(0.f, 0.f, 0.f, 0.f);
        if (row < n) {
            int src = xidx ? xidx[row] : row;
            v = reinterpret_cast<const float4*>(h + (size_t)src * 64)[q];
        }
        reinterpret_cast<float4*>(&sh[node][0])[q] = v;
    }
    __syncthreads();

    int f4 = (tid % F4) * 4;
    int j0 = tid / F4;
    float4 am[NPT], as[NPT];
    float4 bm4 = *reinterpret_cast<const float4*>(bm + f4);
    float4 bs4 = *reinterpret_cast<const float4*>(bs + f4);
    #pragma unroll
    for (int p = 0; p < NPT; ++p) { am[p] = bm4; as[p] = bs4; }

    for (int k4 = 0; k4 < 16; ++k4) {
        float4 hv[NPT];
        #pragma unroll
        for (int p = 0; p < NPT; ++p)
            hv[p] = reinterpret_cast<const float4*>(&sh[j0 + p * NC][0])[k4];
        #pragma unroll
        for (int kk = 0; kk < 4; ++kk) {
            int k = k4 * 4 + kk;
            float4 wm = *reinterpret_cast<const float4*>(Wm + k * H + f4);
            float4 ws = *reinterpret_cast<const float4*>(Ws + k * H + f4);
            #pragma unroll
            for (int p = 0; p < NPT; ++p) {
                float hk = (&hv[p].x)[kk];
                am[p].x += hk * wm.x; am[p].y += hk * wm.y;
                am[p].z += hk * wm.z; am[p].w += hk * wm.w;
                as[p].x += hk * ws.x; as[p].y += hk * ws.y;
                as[p].z += hk * ws.z; as[p].w += hk * ws.w;
            }
        }
    }

    #pragma unroll
    for (int p = 0; p < NPT; ++p) {
        int row = n0 + j0 + p * NC;
        if (row < n) {
            *reinterpret_cast<float4*>(hWm  + (size_t)row * H + f4) = am[p];
            *reinterpret_cast<float4*>(hWsb + (size_t)row * H + f4) = as[p];
        }
    }
}

// ---------------- nscore[n] = hWm[n,:].att ----------------
template <int H>
__global__ void nscore_kernel(const float* __restrict__ hWm, const float* __restrict__ att,
                              float* __restrict__ nscore, int n) {
    int gid = blockIdx.x * blockDim.x + threadIdx.x;
    int wid = gid >> 6, lane = gid & 63;
    if (wid >= n) return;
    float s = 0.f;
    #pragma unroll
    for (int r = 0; r < H / 64; ++r) {
        int hh = lane + r * 64;
        s += hWm[(size_t)wid * H + hh] * att[hh];
    }
    s = wave_sum(s);
    if (lane == 0) nscore[wid] = s;
}

// ---------------- aggregation: per-dst softmax + weighted mean + skip + relu ----------------
template <int H>
__global__ __launch_bounds__(64)
void agg_kernel(const int* __restrict__ csr_off, const int* __restrict__ ce,
                const int* __restrict__ ei, int E,
                const float* __restrict__ nscore, const float* __restrict__ escore,
                const float* __restrict__ ea,
                const float* __restrict__ We, const float* __restrict__ be,
                const float* __restrict__ hWm, const float* __restrict__ hWsb,
                float* __restrict__ hout, int n) {
    constexpr int R = H / 64;
    int node = blockIdx.x;
    if (node >= n) return;
    int lane = threadIdx.x;
    int off0 = csr_off[node];
    int deg = csr_off[node + 1] - off0;

    if (deg == 0) {
        #pragma unroll
        for (int r = 0; r < R; ++r) {
            float v = hWsb[(size_t)node * H + lane + r * 64];
            hout[(size_t)node * H + lane + r * 64] = fmaxf(v, 0.f);
        }
        return;
    }

    float wreg[8][R], bereg[R];
    #pragma unroll
    for (int r = 0; r < R; ++r) {
        bereg[r] = be[lane + r * 64];
        #pragma unroll
        for (int k = 0; k < 8; ++k) wreg[k][r] = We[k * H + lane + r * 64];
    }

    float mx = -1e30f;
    for (int base = 0; base < deg; base += WAVE) {
        int i = base + lane;
        if (i < deg) {
            int e = ce[off0 + i];
            float a = leaky02(nscore[ei[e]] + escore[e]);
            mx = fmaxf(mx, a);
        }
    }
    mx = wave_max(mx);

    float ssum = 0.f;
    for (int base = 0; base < deg; base += WAVE) {
        int i = base + lane;
        if (i < deg) {
            int e = ce[off0 + i];
            float a = leaky02(nscore[ei[e]] + escore[e]);
            ssum += expf(a - mx);
        }
    }
    ssum = wave_sum(ssum);
    float invd = 1.f / (ssum + 1e-16f);

    float acc[R];
    #pragma unroll
    for (int r = 0; r < R; ++r) acc[r] = 0.f;

    for (int base = 0; base < deg; base += WAVE) {
        int cnt = min(WAVE, deg - base);
        int i = base + lane;
        int e = 0, s_ = 0;
        float cf = 0.f;
        if (i < deg) {
            e = ce[off0 + i];
            s_ = ei[e];
            float a = leaky02(nscore[s_] + escore[e]);
            cf = expf(a - mx) * invd;
        }
        for (int j = 0; j < cnt; ++j) {
            int ej = __shfl(e, j);
            int sj = __shfl(s_, j);
            float cj = __shfl(cf, j);
            const float4* p = reinterpret_cast<const float4*>(ea + (size_t)ej * 8);
            float4 a0 = p[0], a1 = p[1];
            #pragma unroll
            for (int r = 0; r < R; ++r) {
                float ew = bereg[r];
                ew += a0.x * wreg[0][r] + a0.y * wreg[1][r] + a0.z * wreg[2][r] + a0.w * wreg[3][r];
                ew += a1.x * wreg[4][r] + a1.y * wreg[5][r] + a1.z * wreg[6][r] + a1.w * wreg[7][r];
                float x = hWm[(size_t)sj * H + lane + r * 64];
                acc[r] += cj * (x + ew);
            }
        }
    }

    float invdeg = 1.f / (float)deg;
    #pragma unroll
    for (int r = 0; r < R; ++r) {
        float v = acc[r] * invdeg + hWsb[(size_t)node * H + lane + r * 64];
        hout[(size_t)node * H + lane + r * 64] = fmaxf(v, 0.f);
    }
}

// ---------------- graph counts via binary search on sorted batchh ----------------
__global__ void graph_cnt_kernel(const int* __restrict__ batchh, int* __restrict__ gcnt,
                                 int n, int G) {
    int b = blockIdx.x * blockDim.x + threadIdx.x;
    if (b >= G) return;
    auto lb = [&](int key) {
        int lo = 0, hi = n;
        while (lo < hi) {
            int mid = (lo + hi) >> 1;
            if (batchh[mid] < key) lo = mid + 1; else hi = mid;
        }
        return lo;
    };
    gcnt[b] = lb(b + 1) - lb(b);
}

__global__ __launch_bounds__(128)
void pool_sum_kernel(const float* __restrict__ h, const int* __restrict__ batchh,
                     float* __restrict__ gsum, int n) {
    int f = threadIdx.x;  // 0..127
    int chunk = (n + gridDim.x - 1) / gridDim.x;
    int start = blockIdx.x * chunk;
    int end = min(n, start + chunk);
    if (start >= end) return;
    float acc = 0.f;
    int cur = batchh[start];
    for (int node = start; node < end; ++node) {
        int b = batchh[node];
        if (b != cur) {
            atomicAdd(&gsum[cur * 128 + f], acc);
            acc = 0.f;
            cur = b;
        }
        acc += h[(size_t)node * 128 + f];
    }
    atomicAdd(&gsum[cur * 128 + f], acc);
}

// ---------------- classifier ----------------
__global__ __launch_bounds__(128)
void classifier_kernel(const float* __restrict__ gsum, const int* __restrict__ gcnt,
                       const float* __restrict__ Wc1, const float* __restrict__ bc1,
                       const float* __restrict__ Wc2, const float* __restrict__ bc2,
                       float* __restrict__ out) {
    int b = blockIdx.x;
    int f = threadIdx.x;
    __shared__ float gm[128];
    __shared__ float t1[128];
    float c = (float)max(gcnt[b], 1);
    gm[f] = gsum[b * 128 + f] / c;
    __syncthreads();
    float acc = bc1[f];
    for (int k = 0; k < 128; ++k) acc += gm[k] * Wc1[k * 128 + f];
    t1[f] = fmaxf(acc, 0.f);
    __syncthreads();
    if (f < 4) {
        float o = bc2[f];
        for (int k = 0; k < 128; ++k) o += t1[k] * Wc2[k * 4 + f];
        out[b * 4 + f] = o;
    }
}

extern "C" void kernel_launch(void* const* d_in, const int* in_sizes, int n_in,
                              void* d_out, int out_size, void* d_ws, size_t ws_size,
                              hipStream_t stream) {
    const int* x      = (const int*)d_in[0];
    const int* ei     = (const int*)d_in[1];
    const float* ea   = (const float*)d_in[2];
    const int* batchh = (const int*)d_in[3];
    const float* emb  = (const float*)d_in[4];
    const float* Wm0 = (const float*)d_in[5];  const float* bm0 = (const float*)d_in[6];
    const float* We0 = (const float*)d_in[7];  const float* be0 = (const float*)d_in[8];
    const float* att0 = (const float*)d_in[9];
    const float* Ws0 = (const float*)d_in[10]; const float* bs0 = (const float*)d_in[11];
    const float* Wm1 = (const float*)d_in[12]; const float* bm1 = (const float*)d_in[13];
    const float* We1 = (const float*)d_in[14]; const float* be1 = (const float*)d_in[15];
    const float* att1 = (const float*)d_in[16];
    const float* Ws1 = (const float*)d_in[17]; const float* bs1 = (const float*)d_in[18];
    const float* Wc1 = (const float*)d_in[19]; const float* bc1 = (const float*)d_in[20];
    const float* Wc2 = (const float*)d_in[21]; const float* bc2 = (const float*)d_in[22];

    const int N = in_sizes[0];
    const int E = in_sizes[1] / 2;
    const int G = 64;
    const int H2 = 128;

    char* w = (char*)d_ws;
    auto alloc = [&](size_t bytes) -> void* {
        void* p = (void*)w;
        w += (bytes + 255) & ~(size_t)255;
        return p;
    };
    float* hbuf   = (float*)alloc((size_t)N * 128 * 4);
    float* hWm    = (float*)alloc((size_t)N * 128 * 4);
    float* hWsb   = (float*)alloc((size_t)N * 128 * 4);
    float* nscore = (float*)alloc((size_t)N * 4);
    float* escore = (float*)alloc((size_t)E * 4);
    int* degcnt   = (int*)alloc((size_t)N * 4);
    int* csroff   = (int*)alloc((size_t)(N + 1) * 4);
    int* cursor   = (int*)alloc((size_t)N * 4);
    int* ce       = (int*)alloc((size_t)E * 4);
    float* watt   = (float*)alloc(16 * 4);
    float* gsum   = (float*)alloc((size_t)G * H2 * 4);
    int* gcnt     = (int*)alloc((size_t)G * 4);

    auto cdiv = [](int a, int b) { return (a + b - 1) / b; };

    hipMemsetAsync(degcnt, 0, (size_t)N * 4, stream);
    hipMemsetAsync(gsum, 0, (size_t)G * H2 * 4, stream);

    // CSR by dst
    count_kernel<<<cdiv(E, 256), 256, 0, stream>>>(ei, E, degcnt);
    scan_kernel<<<1, 1024, 0, stream>>>(degcnt, csroff, cursor, N);
    fill_kernel<<<cdiv(E, 256), 256, 0, stream>>>(ei, E, cursor, ce);

    // ---- layer 0: 64 -> 64 (emb[x] gather fused into nodelin staging) ----
    watt_kernel<<<1, 64, 0, stream>>>(We0, att0, be0, watt, 64);
    escore_kernel<<<cdiv(E, 256), 256, 0, stream>>>(ea, watt, escore, E);
    nodelin_kernel<64, 64><<<cdiv(N, 64), 256, 0, stream>>>(
        emb, x, Wm0, bm0, Ws0, bs0, hWm, hWsb, N);
    nscore_kernel<64><<<cdiv(N, 4), 256, 0, stream>>>(hWm, att0, nscore, N);
    agg_kernel<64><<<N, 64, 0, stream>>>(csroff, ce, ei, E, nscore, escore, ea,
                                         We0, be0, hWm, hWsb, hbuf, N);

    // ---- layer 1: 64 -> 128 ----
    watt_kernel<<<1, 64, 0, stream>>>(We1, att1, be1, watt, 128);
    escore_kernel<<<cdiv(E, 256), 256, 0, stream>>>(ea, watt, escore, E);
    nodelin_kernel<128, 32><<<cdiv(N, 32), 256, 0, stream>>>(
        hbuf, nullptr, Wm1, bm1, Ws1, bs1, hWm, hWsb, N);
    nscore_kernel<128><<<cdiv(N, 4), 256, 0, stream>>>(hWm, att1, nscore, N);
    agg_kernel<128><<<N, 64, 0, stream>>>(csroff, ce, ei, E, nscore, escore, ea,
                                          We1, be1, hWm, hWsb, hbuf, N);

    // ---- global mean pool + classifier ----
    graph_cnt_kernel<<<1, 64, 0, stream>>>(batchh, gcnt, N, G);
    pool_sum_kernel<<<512, 128, 0, stream>>>(hbuf, batchh, gsum, N);
    classifier_kernel<<<G, 128, 0, stream>>>(gsum, gcnt, Wc1, bc1, Wc2, bc2, (float*)d_out);
}

// Round 4
// 526.523 us; speedup vs baseline: 1.7868x; 1.0988x over previous
//
#include <hip/hip_runtime.h>
#include <hip/hip_bf16.h>

#define DEV_INLINE __device__ __forceinline__

static constexpr int WAVE = 64;

DEV_INLINE float wave_max(float v) {
    #pragma unroll
    for (int o = 32; o > 0; o >>= 1) v = fmaxf(v, __shfl_xor(v, o));
    return v;
}
DEV_INLINE float wave_sum(float v) {
    #pragma unroll
    for (int o = 32; o > 0; o >>= 1) v += __shfl_xor(v, o);
    return v;
}
DEV_INLINE float leaky02(float x) { return x > 0.f ? x : 0.2f * x; }
DEV_INLINE unsigned short f2b(float f) {
    __hip_bfloat16 b = __float2bfloat16(f);
    return *reinterpret_cast<unsigned short*>(&b);
}
DEV_INLINE float b2f(unsigned short u) {
    unsigned int x = ((unsigned int)u) << 16;
    return __uint_as_float(x);
}

// ---------------- CSR build ----------------
__global__ void count_kernel(const int* __restrict__ ei, int E, int* __restrict__ deg) {
    int i = blockIdx.x * blockDim.x + threadIdx.x;
    if (i >= E) return;
    atomicAdd(&deg[ei[E + i]], 1);
}

__global__ __launch_bounds__(1024)
void scan_kernel(const int* __restrict__ deg, int* __restrict__ off,
                 int* __restrict__ cursor, int n) {
    __shared__ int sums[1024];
    __shared__ int carryS;
    int tid = threadIdx.x;
    if (tid == 0) carryS = 0;
    __syncthreads();
    const int PER = 16;
    const int TILE = 1024 * PER;
    for (int base = 0; base < n; base += TILE) {
        int v[PER];
        int s = 0;
        int i0 = base + tid * PER;
        #pragma unroll
        for (int j = 0; j < PER; ++j) {
            int i = i0 + j;
            int x = (i < n) ? deg[i] : 0;
            v[j] = x; s += x;
        }
        sums[tid] = s;
        __syncthreads();
        for (int d = 1; d < 1024; d <<= 1) {
            int t = (tid >= d) ? sums[tid - d] : 0;
            __syncthreads();
            sums[tid] += t;
            __syncthreads();
        }
        int incl = sums[tid];
        int excl = incl - s;
        int total = sums[1023];
        int run = carryS + excl;
        #pragma unroll
        for (int j = 0; j < PER; ++j) {
            int i = i0 + j;
            if (i < n) { off[i] = run; cursor[i] = run; }
            run += v[j];
        }
        __syncthreads();
        if (tid == 0) carryS += total;
        __syncthreads();
    }
    if (tid == 0) off[n] = carryS;
}

__global__ void fill_kernel(const int* __restrict__ ei, int E,
                            int* __restrict__ cursor, int* __restrict__ ce) {
    int i = blockIdx.x * blockDim.x + threadIdx.x;
    if (i >= E) return;
    int d = ei[E + i];
    int pos = atomicAdd(&cursor[d], 1);
    ce[pos] = i;
}

// ---------------- watt[k] = sum_h We[k,h]*att[h], watt[8] = be.att ----------------
__global__ void watt_kernel(const float* __restrict__ We, const float* __restrict__ att,
                            const float* __restrict__ be, float* __restrict__ watt, int H) {
    int lane = threadIdx.x;
    for (int k = 0; k < 8; ++k) {
        float s = 0.f;
        for (int h = lane; h < H; h += WAVE) s += We[k * H + h] * att[h];
        s = wave_sum(s);
        if (lane == 0) watt[k] = s;
    }
    float s = 0.f;
    for (int h = lane; h < H; h += WAVE) s += be[h] * att[h];
    s = wave_sum(s);
    if (lane == 0) watt[8] = s;
}

// ---------------- escore[e] = ea[e,:].watt + watt[8] ----------------
__global__ void escore_kernel(const float* __restrict__ ea, const float* __restrict__ watt,
                              float* __restrict__ escore, int E) {
    int e = blockIdx.x * blockDim.x + threadIdx.x;
    if (e >= E) return;
    const float4* p = reinterpret_cast<const float4*>(ea + (size_t)e * 8);
    float4 a0 = p[0], a1 = p[1];
    float s = watt[8];
    s += a0.x * watt[0] + a0.y * watt[1] + a0.z * watt[2] + a0.w * watt[3];
    s += a1.x * watt[4] + a1.y * watt[5] + a1.z * watt[6] + a1.w * watt[7];
    escore[e] = s;
}

// ---------------- node linear (LDS-tiled register-blocked GEMM) ----------------
// hWm (bf16) = h@Wm+bm ; hWsb (fp32) = h@Ws+bs. Optional xidx fuses emb[x] gather.
template <int H, int NB>
__global__ __launch_bounds__(256)
void nodelin_kernel(const float* __restrict__ h, const int* __restrict__ xidx,
                    const float* __restrict__ Wm, const float* __restrict__ bm,
                    const float* __restrict__ Ws, const float* __restrict__ bs,
                    unsigned short* __restrict__ hWmb, float* __restrict__ hWsb, int n) {
    constexpr int F4  = H / 4;
    constexpr int NC  = 256 / F4;
    constexpr int NPT = NB / NC;
    constexpr int LDW = 68;
    __shared__ float sh[NB][LDW];
    int n0 = blockIdx.x * NB;
    int tid = threadIdx.x;

    for (int i = tid; i < NB * 16; i += 256) {
        int node = i >> 4, q = i & 15;
        int row = n0 + node;
        float4 v = make_float4(0.f, 0.f, 0.f, 0.f);
        if (row < n) {
            int src = xidx ? xidx[row] : row;
            v = reinterpret_cast<const float4*>(h + (size_t)src * 64)[q];
        }
        reinterpret_cast<float4*>(&sh[node][0])[q] = v;
    }
    __syncthreads();

    int f4 = (tid % F4) * 4;
    int j0 = tid / F4;
    float4 am[NPT], as[NPT];
    float4 bm4 = *reinterpret_cast<const float4*>(bm + f4);
    float4 bs4 = *reinterpret_cast<const float4*>(bs + f4);
    #pragma unroll
    for (int p = 0; p < NPT; ++p) { am[p] = bm4; as[p] = bs4; }

    for (int k4 = 0; k4 < 16; ++k4) {
        float4 hv[NPT];
        #pragma unroll
        for (int p = 0; p < NPT; ++p)
            hv[p] = reinterpret_cast<const float4*>(&sh[j0 + p * NC][0])[k4];
        #pragma unroll
        for (int kk = 0; kk < 4; ++kk) {
            int k = k4 * 4 + kk;
            float4 wm = *reinterpret_cast<const float4*>(Wm + k * H + f4);
            float4 ws = *reinterpret_cast<const float4*>(Ws + k * H + f4);
            #pragma unroll
            for (int p = 0; p < NPT; ++p) {
                float hk = (&hv[p].x)[kk];
                am[p].x += hk * wm.x; am[p].y += hk * wm.y;
                am[p].z += hk * wm.z; am[p].w += hk * wm.w;
                as[p].x += hk * ws.x; as[p].y += hk * ws.y;
                as[p].z += hk * ws.z; as[p].w += hk * ws.w;
            }
        }
    }

    #pragma unroll
    for (int p = 0; p < NPT; ++p) {
        int row = n0 + j0 + p * NC;
        if (row < n) {
            ushort4 ob;
            ob.x = f2b(am[p].x); ob.y = f2b(am[p].y);
            ob.z = f2b(am[p].z); ob.w = f2b(am[p].w);
            *reinterpret_cast<ushort4*>(hWmb + (size_t)row * H + f4) = ob;
            *reinterpret_cast<float4*>(hWsb + (size_t)row * H + f4) = as[p];
        }
    }
}

// ---------------- nscore[n] = hWm[n,:].att (bf16 table) ----------------
template <int H>
__global__ void nscore_kernel(const unsigned short* __restrict__ hWmb,
                              const float* __restrict__ att,
                              float* __restrict__ nscore, int n) {
    constexpr int R = H / 64;
    int gid = blockIdx.x * blockDim.x + threadIdx.x;
    int wid = gid >> 6, lane = gid & 63;
    if (wid >= n) return;
    float s = 0.f;
    if constexpr (R == 2) {
        unsigned int g = *reinterpret_cast<const unsigned int*>(hWmb + (size_t)wid * H + 2 * lane);
        float2 at = *reinterpret_cast<const float2*>(att + 2 * lane);
        s = b2f((unsigned short)(g & 0xffff)) * at.x + b2f((unsigned short)(g >> 16)) * at.y;
    } else {
        s = b2f(hWmb[(size_t)wid * H + lane]) * att[lane];
    }
    s = wave_sum(s);
    if (lane == 0) nscore[wid] = s;
}

// ---------------- aggregation: fused softmax + weighted mean + skip + relu ----------------
// Lane owns features f = lane*R + r. Uses identity sum_j c_j*(We^T ea_j + be)
//   = We^T (sum_j c_j ea_j) + be  (since sum c_j = 1) to hoist ea@We out of the j-loop.
template <int H>
__global__ __launch_bounds__(64)
void agg_kernel(const int* __restrict__ csr_off, const int* __restrict__ ce,
                const int* __restrict__ ei, int E,
                const float* __restrict__ nscore, const float* __restrict__ escore,
                const float* __restrict__ ea,
                const float* __restrict__ We, const float* __restrict__ be,
                const unsigned short* __restrict__ hWmb, const float* __restrict__ hWsb,
                float* __restrict__ hout, int n) {
    constexpr int R = H / 64;
    int node = blockIdx.x;
    if (node >= n) return;
    int lane = threadIdx.x;
    int off0 = csr_off[node];
    int deg = csr_off[node + 1] - off0;
    int fbase = lane * R;

    if (deg == 0) {
        #pragma unroll
        for (int r = 0; r < R; ++r) {
            float v = hWsb[(size_t)node * H + fbase + r];
            hout[(size_t)node * H + fbase + r] = fmaxf(v, 0.f);
        }
        return;
    }

    float cea[8];
    #pragma unroll
    for (int k = 0; k < 8; ++k) cea[k] = 0.f;
    float acc[R];
    #pragma unroll
    for (int r = 0; r < R; ++r) acc[r] = 0.f;

    if (deg <= WAVE) {
        // ---- fused single-chunk path (the ~always case) ----
        int e = 0, s_ = 0;
        float a = -1e30f;
        if (lane < deg) {
            e = ce[off0 + lane];
            s_ = ei[e];
            a = leaky02(nscore[s_] + escore[e]);
        }
        float mx = wave_max(a);
        float cf = (lane < deg) ? expf(a - mx) : 0.f;
        float ssum = wave_sum(cf);
        cf *= 1.f / (ssum + 1e-16f);
        if (lane < deg) {
            const float4* p = reinterpret_cast<const float4*>(ea + (size_t)e * 8);
            float4 a0 = p[0], a1 = p[1];
            cea[0] = cf * a0.x; cea[1] = cf * a0.y; cea[2] = cf * a0.z; cea[3] = cf * a0.w;
            cea[4] = cf * a1.x; cea[5] = cf * a1.y; cea[6] = cf * a1.z; cea[7] = cf * a1.w;
        }
        #pragma unroll 4
        for (int j = 0; j < deg; ++j) {
            int sj = __shfl(s_, j);
            float cj = __shfl(cf, j);
            if constexpr (R == 2) {
                unsigned int g = *reinterpret_cast<const unsigned int*>(
                    hWmb + (size_t)sj * H + 2 * lane);
                acc[0] += cj * b2f((unsigned short)(g & 0xffff));
                acc[1] += cj * b2f((unsigned short)(g >> 16));
            } else {
                acc[0] += cj * b2f(hWmb[(size_t)sj * H + lane]);
            }
        }
    } else {
        // ---- generic fallback (deg > 64; ~never for Binomial(E,1/N)) ----
        float mx = -1e30f;
        for (int base = 0; base < deg; base += WAVE) {
            int i = base + lane;
            if (i < deg) {
                int e = ce[off0 + i];
                float a = leaky02(nscore[ei[e]] + escore[e]);
                mx = fmaxf(mx, a);
            }
        }
        mx = wave_max(mx);
        float ssum = 0.f;
        for (int base = 0; base < deg; base += WAVE) {
            int i = base + lane;
            if (i < deg) {
                int e = ce[off0 + i];
                float a = leaky02(nscore[ei[e]] + escore[e]);
                ssum += expf(a - mx);
            }
        }
        ssum = wave_sum(ssum);
        float invs = 1.f / (ssum + 1e-16f);
        for (int base = 0; base < deg; base += WAVE) {
            int cnt = min(WAVE, deg - base);
            int i = base + lane;
            int e = 0, s_ = 0;
            float cf = 0.f;
            if (i < deg) {
                e = ce[off0 + i];
                s_ = ei[e];
                float a = leaky02(nscore[s_] + escore[e]);
                cf = expf(a - mx) * invs;
                const float4* p = reinterpret_cast<const float4*>(ea + (size_t)e * 8);
                float4 a0 = p[0], a1 = p[1];
                cea[0] += cf * a0.x; cea[1] += cf * a0.y; cea[2] += cf * a0.z; cea[3] += cf * a0.w;
                cea[4] += cf * a1.x; cea[5] += cf * a1.y; cea[6] += cf * a1.z; cea[7] += cf * a1.w;
            }
            for (int j = 0; j < cnt; ++j) {
                int sj = __shfl(s_, j);
                float cj = __shfl(cf, j);
                if constexpr (R == 2) {
                    unsigned int g = *reinterpret_cast<const unsigned int*>(
                        hWmb + (size_t)sj * H + 2 * lane);
                    acc[0] += cj * b2f((unsigned short)(g & 0xffff));
                    acc[1] += cj * b2f((unsigned short)(g >> 16));
                } else {
                    acc[0] += cj * b2f(hWmb[(size_t)sj * H + lane]);
                }
            }
        }
    }

    // reduce cea across lanes (result broadcast to all lanes by xor-butterfly)
    #pragma unroll
    for (int k = 0; k < 8; ++k) cea[k] = wave_sum(cea[k]);

    float invdeg = 1.f / (float)deg;
    #pragma unroll
    for (int r = 0; r < R; ++r) {
        float ew = be[fbase + r];
        #pragma unroll
        for (int k = 0; k < 8; ++k) ew += cea[k] * We[k * H + fbase + r];
        float v = (acc[r] + ew) * invdeg + hWsb[(size_t)node * H + fbase + r];
        hout[(size_t)node * H + fbase + r] = fmaxf(v, 0.f);
    }
}

// ---------------- graph counts via binary search on sorted batchh ----------------
__global__ void graph_cnt_kernel(const int* __restrict__ batchh, int* __restrict__ gcnt,
                                 int n, int G) {
    int b = blockIdx.x * blockDim.x + threadIdx.x;
    if (b >= G) return;
    auto lb = [&](int key) {
        int lo = 0, hi = n;
        while (lo < hi) {
            int mid = (lo + hi) >> 1;
            if (batchh[mid] < key) lo = mid + 1; else hi = mid;
        }
        return lo;
    };
    gcnt[b] = lb(b + 1) - lb(b);
}

__global__ __launch_bounds__(128)
void pool_sum_kernel(const float* __restrict__ h, const int* __restrict__ batchh,
                     float* __restrict__ gsum, int n) {
    int f = threadIdx.x;
    int chunk = (n + gridDim.x - 1) / gridDim.x;
    int start = blockIdx.x * chunk;
    int end = min(n, start + chunk);
    if (start >= end) return;
    float acc = 0.f;
    int cur = batchh[start];
    for (int node = start; node < end; ++node) {
        int b = batchh[node];
        if (b != cur) {
            atomicAdd(&gsum[cur * 128 + f], acc);
            acc = 0.f;
            cur = b;
        }
        acc += h[(size_t)node * 128 + f];
    }
    atomicAdd(&gsum[cur * 128 + f], acc);
}

// ---------------- classifier ----------------
__global__ __launch_bounds__(128)
void classifier_kernel(const float* __restrict__ gsum, const int* __restrict__ gcnt,
                       const float* __restrict__ Wc1, const float* __restrict__ bc1,
                       const float* __restrict__ Wc2, const float* __restrict__ bc2,
                       float* __restrict__ out) {
    int b = blockIdx.x;
    int f = threadIdx.x;
    __shared__ float gm[128];
    __shared__ float t1[128];
    float c = (float)max(gcnt[b], 1);
    gm[f] = gsum[b * 128 + f] / c;
    __syncthreads();
    float acc = bc1[f];
    for (int k = 0; k < 128; ++k) acc += gm[k] * Wc1[k * 128 + f];
    t1[f] = fmaxf(acc, 0.f);
    __syncthreads();
    if (f < 4) {
        float o = bc2[f];
        for (int k = 0; k < 128; ++k) o += t1[k] * Wc2[k * 4 + f];
        out[b * 4 + f] = o;
    }
}

extern "C" void kernel_launch(void* const* d_in, const int* in_sizes, int n_in,
                              void* d_out, int out_size, void* d_ws, size_t ws_size,
                              hipStream_t stream) {
    const int* x      = (const int*)d_in[0];
    const int* ei     = (const int*)d_in[1];
    const float* ea   = (const float*)d_in[2];
    const int* batchh = (const int*)d_in[3];
    const float* emb  = (const float*)d_in[4];
    const float* Wm0 = (const float*)d_in[5];  const float* bm0 = (const float*)d_in[6];
    const float* We0 = (const float*)d_in[7];  const float* be0 = (const float*)d_in[8];
    const float* att0 = (const float*)d_in[9];
    const float* Ws0 = (const float*)d_in[10]; const float* bs0 = (const float*)d_in[11];
    const float* Wm1 = (const float*)d_in[12]; const float* bm1 = (const float*)d_in[13];
    const float* We1 = (const float*)d_in[14]; const float* be1 = (const float*)d_in[15];
    const float* att1 = (const float*)d_in[16];
    const float* Ws1 = (const float*)d_in[17]; const float* bs1 = (const float*)d_in[18];
    const float* Wc1 = (const float*)d_in[19]; const float* bc1 = (const float*)d_in[20];
    const float* Wc2 = (const float*)d_in[21]; const float* bc2 = (const float*)d_in[22];

    const int N = in_sizes[0];
    const int E = in_sizes[1] / 2;
    const int G = 64;
    const int H2 = 128;

    char* w = (char*)d_ws;
    auto alloc = [&](size_t bytes) -> void* {
        void* p = (void*)w;
        w += (bytes + 255) & ~(size_t)255;
        return p;
    };
    float* hbuf            = (float*)alloc((size_t)N * 128 * 4);
    unsigned short* hWmb   = (unsigned short*)alloc((size_t)N * 128 * 2);
    float* hWsb            = (float*)alloc((size_t)N * 128 * 4);
    float* nscore          = (float*)alloc((size_t)N * 4);
    float* escore          = (float*)alloc((size_t)E * 4);
    int* degcnt            = (int*)alloc((size_t)N * 4);
    int* csroff            = (int*)alloc((size_t)(N + 1) * 4);
    int* cursor            = (int*)alloc((size_t)N * 4);
    int* ce                = (int*)alloc((size_t)E * 4);
    float* watt            = (float*)alloc(16 * 4);
    float* gsum            = (float*)alloc((size_t)G * H2 * 4);
    int* gcnt              = (int*)alloc((size_t)G * 4);

    auto cdiv = [](int a, int b) { return (a + b - 1) / b; };

    hipMemsetAsync(degcnt, 0, (size_t)N * 4, stream);
    hipMemsetAsync(gsum, 0, (size_t)G * H2 * 4, stream);

    // CSR by dst
    count_kernel<<<cdiv(E, 256), 256, 0, stream>>>(ei, E, degcnt);
    scan_kernel<<<1, 1024, 0, stream>>>(degcnt, csroff, cursor, N);
    fill_kernel<<<cdiv(E, 256), 256, 0, stream>>>(ei, E, cursor, ce);

    // ---- layer 0: 64 -> 64 ----
    watt_kernel<<<1, 64, 0, stream>>>(We0, att0, be0, watt, 64);
    escore_kernel<<<cdiv(E, 256), 256, 0, stream>>>(ea, watt, escore, E);
    nodelin_kernel<64, 64><<<cdiv(N, 64), 256, 0, stream>>>(
        emb, x, Wm0, bm0, Ws0, bs0, hWmb, hWsb, N);
    nscore_kernel<64><<<cdiv(N, 4), 256, 0, stream>>>(hWmb, att0, nscore, N);
    agg_kernel<64><<<N, 64, 0, stream>>>(csroff, ce, ei, E, nscore, escore, ea,
                                         We0, be0, hWmb, hWsb, hbuf, N);

    // ---- layer 1: 64 -> 128 ----
    watt_kernel<<<1, 64, 0, stream>>>(We1, att1, be1, watt, 128);
    escore_kernel<<<cdiv(E, 256), 256, 0, stream>>>(ea, watt, escore, E);
    nodelin_kernel<128, 32><<<cdiv(N, 32), 256, 0, stream>>>(
        hbuf, nullptr, Wm1, bm1, Ws1, bs1, hWmb, hWsb, N);
    nscore_kernel<128><<<cdiv(N, 4), 256, 0, stream>>>(hWmb, att1, nscore, N);
    agg_kernel<128><<<N, 64, 0, stream>>>(csroff, ce, ei, E, nscore, escore, ea,
                                          We1, be1, hWmb, hWsb, hbuf, N);

    // ---- global mean pool + classifier ----
    graph_cnt_kernel<<<1, 64, 0, stream>>>(batchh, gcnt, N, G);
    pool_sum_kernel<<<512, 128, 0, stream>>>(hbuf, batchh, gsum, N);
    classifier_kernel<<<G, 128, 0, stream>>>(gsum, gcnt, Wc1, bc1, Wc2, bc2, (float*)d_out);
}

// Round 5
// 518.069 us; speedup vs baseline: 1.8160x; 1.0163x over previous
//
#include <hip/hip_runtime.h>
#include <hip/hip_bf16.h>

#define DEV_INLINE __device__ __forceinline__

static constexpr int WAVE = 64;
static constexpr float FP8_SCALE = 64.0f;
static constexpr float FP8_INV   = 1.0f / 64.0f;

DEV_INLINE float wave_max(float v) {
    #pragma unroll
    for (int o = 32; o > 0; o >>= 1) v = fmaxf(v, __shfl_xor(v, o));
    return v;
}
DEV_INLINE float wave_sum(float v) {
    #pragma unroll
    for (int o = 32; o > 0; o >>= 1) v += __shfl_xor(v, o);
    return v;
}
DEV_INLINE float leaky02(float x) { return x > 0.f ? x : 0.2f * x; }

// ---------------- CSR build ----------------
__global__ void count_kernel(const int* __restrict__ ei, int E, int* __restrict__ deg) {
    int i = blockIdx.x * blockDim.x + threadIdx.x;
    if (i >= E) return;
    atomicAdd(&deg[ei[E + i]], 1);
}

__global__ __launch_bounds__(1024)
void scan_kernel(const int* __restrict__ deg, int* __restrict__ off,
                 int* __restrict__ cursor, int n) {
    __shared__ int sums[1024];
    __shared__ int carryS;
    int tid = threadIdx.x;
    if (tid == 0) carryS = 0;
    __syncthreads();
    const int PER = 16;
    const int TILE = 1024 * PER;
    for (int base = 0; base < n; base += TILE) {
        int v[PER];
        int s = 0;
        int i0 = base + tid * PER;
        #pragma unroll
        for (int j = 0; j < PER; ++j) {
            int i = i0 + j;
            int x = (i < n) ? deg[i] : 0;
            v[j] = x; s += x;
        }
        sums[tid] = s;
        __syncthreads();
        for (int d = 1; d < 1024; d <<= 1) {
            int t = (tid >= d) ? sums[tid - d] : 0;
            __syncthreads();
            sums[tid] += t;
            __syncthreads();
        }
        int incl = sums[tid];
        int excl = incl - s;
        int total = sums[1023];
        int run = carryS + excl;
        #pragma unroll
        for (int j = 0; j < PER; ++j) {
            int i = i0 + j;
            if (i < n) { off[i] = run; cursor[i] = run; }
            run += v[j];
        }
        __syncthreads();
        if (tid == 0) carryS += total;
        __syncthreads();
    }
    if (tid == 0) off[n] = carryS;
}

__global__ void fill_kernel(const int* __restrict__ ei, int E,
                            int* __restrict__ cursor, int* __restrict__ ce) {
    int i = blockIdx.x * blockDim.x + threadIdx.x;
    if (i >= E) return;
    int d = ei[E + i];
    int pos = atomicAdd(&cursor[d], 1);
    ce[pos] = i;
}

// ---------------- watt[k] = sum_h We[k,h]*att[h], watt[8] = be.att ----------------
__global__ void watt_kernel(const float* __restrict__ We, const float* __restrict__ att,
                            const float* __restrict__ be, float* __restrict__ watt, int H) {
    int lane = threadIdx.x;
    for (int k = 0; k < 8; ++k) {
        float s = 0.f;
        for (int h = lane; h < H; h += WAVE) s += We[k * H + h] * att[h];
        s = wave_sum(s);
        if (lane == 0) watt[k] = s;
    }
    float s = 0.f;
    for (int h = lane; h < H; h += WAVE) s += be[h] * att[h];
    s = wave_sum(s);
    if (lane == 0) watt[8] = s;
}

// ---------------- escore[e] = ea[e,:].watt + watt[8] ----------------
__global__ void escore_kernel(const float* __restrict__ ea, const float* __restrict__ watt,
                              float* __restrict__ escore, int E) {
    int e = blockIdx.x * blockDim.x + threadIdx.x;
    if (e >= E) return;
    const float4* p = reinterpret_cast<const float4*>(ea + (size_t)e * 8);
    float4 a0 = p[0], a1 = p[1];
    float s = watt[8];
    s += a0.x * watt[0] + a0.y * watt[1] + a0.z * watt[2] + a0.w * watt[3];
    s += a1.x * watt[4] + a1.y * watt[5] + a1.z * watt[6] + a1.w * watt[7];
    escore[e] = s;
}

// ---------------- node linear (LDS-tiled register-blocked GEMM) ----------------
// hWm8 (fp8 e4m3, x64 scale) = h@Wm+bm ; hWsb (fp32) = h@Ws+bs.
// Fused: nscore[row] = (h@Wm+bm).att (fp32, subgroup shfl_xor reduction).
// Optional xidx fuses emb[x] gather.
template <int H, int NB>
__global__ __launch_bounds__(256)
void nodelin_kernel(const float* __restrict__ h, const int* __restrict__ xidx,
                    const float* __restrict__ Wm, const float* __restrict__ bm,
                    const float* __restrict__ Ws, const float* __restrict__ bs,
                    const float* __restrict__ att,
                    unsigned char* __restrict__ hWm8, float* __restrict__ hWsb,
                    float* __restrict__ nscore, int n) {
    constexpr int F4  = H / 4;
    constexpr int NC  = 256 / F4;
    constexpr int NPT = NB / NC;
    constexpr int LDW = 68;
    __shared__ float sh[NB][LDW];
    int n0 = blockIdx.x * NB;
    int tid = threadIdx.x;

    for (int i = tid; i < NB * 16; i += 256) {
        int node = i >> 4, q = i & 15;
        int row = n0 + node;
        float4 v = make_float4(0.f, 0.f, 0.f, 0.f);
        if (row < n) {
            int src = xidx ? xidx[row] : row;
            v = reinterpret_cast<const float4*>(h + (size_t)src * 64)[q];
        }
        reinterpret_cast<float4*>(&sh[node][0])[q] = v;
    }
    __syncthreads();

    int f4 = (tid % F4) * 4;
    int j0 = tid / F4;
    float4 am[NPT], as[NPT];
    float4 bm4 = *reinterpret_cast<const float4*>(bm + f4);
    float4 bs4 = *reinterpret_cast<const float4*>(bs + f4);
    #pragma unroll
    for (int p = 0; p < NPT; ++p) { am[p] = bm4; as[p] = bs4; }

    for (int k4 = 0; k4 < 16; ++k4) {
        float4 hv[NPT];
        #pragma unroll
        for (int p = 0; p < NPT; ++p)
            hv[p] = reinterpret_cast<const float4*>(&sh[j0 + p * NC][0])[k4];
        #pragma unroll
        for (int kk = 0; kk < 4; ++kk) {
            int k = k4 * 4 + kk;
            float4 wm = *reinterpret_cast<const float4*>(Wm + k * H + f4);
            float4 ws = *reinterpret_cast<const float4*>(Ws + k * H + f4);
            #pragma unroll
            for (int p = 0; p < NPT; ++p) {
                float hk = (&hv[p].x)[kk];
                am[p].x += hk * wm.x; am[p].y += hk * wm.y;
                am[p].z += hk * wm.z; am[p].w += hk * wm.w;
                as[p].x += hk * ws.x; as[p].y += hk * ws.y;
                as[p].z += hk * ws.z; as[p].w += hk * ws.w;
            }
        }
    }

    float4 at4 = *reinterpret_cast<const float4*>(att + f4);
    #pragma unroll
    for (int p = 0; p < NPT; ++p) {
        int row = n0 + j0 + p * NC;
        // fused nscore: dot(m, att) reduced across the F4 lanes of this node
        float sc = am[p].x * at4.x + am[p].y * at4.y + am[p].z * at4.z + am[p].w * at4.w;
        #pragma unroll
        for (int o = 1; o < F4; o <<= 1) sc += __shfl_xor(sc, o);
        if (row < n) {
            int pk = 0;
            pk = __builtin_amdgcn_cvt_pk_fp8_f32(am[p].x * FP8_SCALE, am[p].y * FP8_SCALE, pk, false);
            pk = __builtin_amdgcn_cvt_pk_fp8_f32(am[p].z * FP8_SCALE, am[p].w * FP8_SCALE, pk, true);
            *reinterpret_cast<unsigned int*>(hWm8 + (size_t)row * H + f4) = (unsigned int)pk;
            *reinterpret_cast<float4*>(hWsb + (size_t)row * H + f4) = as[p];
            if ((tid % F4) == 0) nscore[row] = sc;
        }
    }
}

// ---------------- aggregation: fused softmax + weighted mean + skip + relu ----------------
// Lane owns features f = lane*R + r. Identity: sum_j c_j*(We^T ea_j + be)
//   = We^T (sum_j c_j ea_j) + be (sum c_j = 1). Message table is fp8 e4m3 (x64).
template <int H>
__global__ __launch_bounds__(64)
void agg_kernel(const int* __restrict__ csr_off, const int* __restrict__ ce,
                const int* __restrict__ ei, int E,
                const float* __restrict__ nscore, const float* __restrict__ escore,
                const float* __restrict__ ea,
                const float* __restrict__ We, const float* __restrict__ be,
                const unsigned char* __restrict__ hWm8, const float* __restrict__ hWsb,
                float* __restrict__ hout, int n) {
    constexpr int R = H / 64;
    int node = blockIdx.x;
    if (node >= n) return;
    int lane = threadIdx.x;
    int off0 = csr_off[node];
    int deg = csr_off[node + 1] - off0;
    int fbase = lane * R;

    if (deg == 0) {
        #pragma unroll
        for (int r = 0; r < R; ++r) {
            float v = hWsb[(size_t)node * H + fbase + r];
            hout[(size_t)node * H + fbase + r] = fmaxf(v, 0.f);
        }
        return;
    }

    float cea[8];
    #pragma unroll
    for (int k = 0; k < 8; ++k) cea[k] = 0.f;
    float acc[R];
    #pragma unroll
    for (int r = 0; r < R; ++r) acc[r] = 0.f;

    if (deg <= WAVE) {
        int e = 0, s_ = 0;
        float a = -1e30f;
        if (lane < deg) {
            e = ce[off0 + lane];
            s_ = ei[e];
            a = leaky02(nscore[s_] + escore[e]);
        }
        float mx = wave_max(a);
        float cf = (lane < deg) ? expf(a - mx) : 0.f;
        float ssum = wave_sum(cf);
        cf *= 1.f / (ssum + 1e-16f);
        if (lane < deg) {
            const float4* p = reinterpret_cast<const float4*>(ea + (size_t)e * 8);
            float4 a0 = p[0], a1 = p[1];
            cea[0] = cf * a0.x; cea[1] = cf * a0.y; cea[2] = cf * a0.z; cea[3] = cf * a0.w;
            cea[4] = cf * a1.x; cea[5] = cf * a1.y; cea[6] = cf * a1.z; cea[7] = cf * a1.w;
        }
        #pragma unroll 4
        for (int j = 0; j < deg; ++j) {
            int sj = __shfl(s_, j);
            float cj = __shfl(cf, j);
            if constexpr (R == 2) {
                unsigned short u = *reinterpret_cast<const unsigned short*>(
                    hWm8 + (size_t)sj * H + 2 * lane);
                acc[0] += cj * __builtin_amdgcn_cvt_f32_fp8((int)u, 0);
                acc[1] += cj * __builtin_amdgcn_cvt_f32_fp8((int)u, 1);
            } else {
                unsigned char u = hWm8[(size_t)sj * H + lane];
                acc[0] += cj * __builtin_amdgcn_cvt_f32_fp8((int)u, 0);
            }
        }
    } else {
        float mx = -1e30f;
        for (int base = 0; base < deg; base += WAVE) {
            int i = base + lane;
            if (i < deg) {
                int e = ce[off0 + i];
                float a = leaky02(nscore[ei[e]] + escore[e]);
                mx = fmaxf(mx, a);
            }
        }
        mx = wave_max(mx);
        float ssum = 0.f;
        for (int base = 0; base < deg; base += WAVE) {
            int i = base + lane;
            if (i < deg) {
                int e = ce[off0 + i];
                float a = leaky02(nscore[ei[e]] + escore[e]);
                ssum += expf(a - mx);
            }
        }
        ssum = wave_sum(ssum);
        float invs = 1.f / (ssum + 1e-16f);
        for (int base = 0; base < deg; base += WAVE) {
            int cnt = min(WAVE, deg - base);
            int i = base + lane;
            int e = 0, s_ = 0;
            float cf = 0.f;
            if (i < deg) {
                e = ce[off0 + i];
                s_ = ei[e];
                float a = leaky02(nscore[s_] + escore[e]);
                cf = expf(a - mx) * invs;
                const float4* p = reinterpret_cast<const float4*>(ea + (size_t)e * 8);
                float4 a0 = p[0], a1 = p[1];
                cea[0] += cf * a0.x; cea[1] += cf * a0.y; cea[2] += cf * a0.z; cea[3] += cf * a0.w;
                cea[4] += cf * a1.x; cea[5] += cf * a1.y; cea[6] += cf * a1.z; cea[7] += cf * a1.w;
            }
            for (int j = 0; j < cnt; ++j) {
                int sj = __shfl(s_, j);
                float cj = __shfl(cf, j);
                if constexpr (R == 2) {
                    unsigned short u = *reinterpret_cast<const unsigned short*>(
                        hWm8 + (size_t)sj * H + 2 * lane);
                    acc[0] += cj * __builtin_amdgcn_cvt_f32_fp8((int)u, 0);
                    acc[1] += cj * __builtin_amdgcn_cvt_f32_fp8((int)u, 1);
                } else {
                    unsigned char u = hWm8[(size_t)sj * H + lane];
                    acc[0] += cj * __builtin_amdgcn_cvt_f32_fp8((int)u, 0);
                }
            }
        }
    }

    #pragma unroll
    for (int k = 0; k < 8; ++k) cea[k] = wave_sum(cea[k]);

    float invdeg = 1.f / (float)deg;
    #pragma unroll
    for (int r = 0; r < R; ++r) {
        float ew = be[fbase + r];
        #pragma unroll
        for (int k = 0; k < 8; ++k) ew += cea[k] * We[k * H + fbase + r];
        float v = (acc[r] * FP8_INV + ew) * invdeg + hWsb[(size_t)node * H + fbase + r];
        hout[(size_t)node * H + fbase + r] = fmaxf(v, 0.f);
    }
}

// ---------------- graph counts via binary search on sorted batchh ----------------
__global__ void graph_cnt_kernel(const int* __restrict__ batchh, int* __restrict__ gcnt,
                                 int n, int G) {
    int b = blockIdx.x * blockDim.x + threadIdx.x;
    if (b >= G) return;
    auto lb = [&](int key) {
        int lo = 0, hi = n;
        while (lo < hi) {
            int mid = (lo + hi) >> 1;
            if (batchh[mid] < key) lo = mid + 1; else hi = mid;
        }
        return lo;
    };
    gcnt[b] = lb(b + 1) - lb(b);
}

__global__ __launch_bounds__(128)
void pool_sum_kernel(const float* __restrict__ h, const int* __restrict__ batchh,
                     float* __restrict__ gsum, int n) {
    int f = threadIdx.x;
    int chunk = (n + gridDim.x - 1) / gridDim.x;
    int start = blockIdx.x * chunk;
    int end = min(n, start + chunk);
    if (start >= end) return;
    float acc = 0.f;
    int cur = batchh[start];
    for (int node = start; node < end; ++node) {
        int b = batchh[node];
        if (b != cur) {
            atomicAdd(&gsum[cur * 128 + f], acc);
            acc = 0.f;
            cur = b;
        }
        acc += h[(size_t)node * 128 + f];
    }
    atomicAdd(&gsum[cur * 128 + f], acc);
}

// ---------------- classifier ----------------
__global__ __launch_bounds__(128)
void classifier_kernel(const float* __restrict__ gsum, const int* __restrict__ gcnt,
                       const float* __restrict__ Wc1, const float* __restrict__ bc1,
                       const float* __restrict__ Wc2, const float* __restrict__ bc2,
                       float* __restrict__ out) {
    int b = blockIdx.x;
    int f = threadIdx.x;
    __shared__ float gm[128];
    __shared__ float t1[128];
    float c = (float)max(gcnt[b], 1);
    gm[f] = gsum[b * 128 + f] / c;
    __syncthreads();
    float acc = bc1[f];
    for (int k = 0; k < 128; ++k) acc += gm[k] * Wc1[k * 128 + f];
    t1[f] = fmaxf(acc, 0.f);
    __syncthreads();
    if (f < 4) {
        float o = bc2[f];
        for (int k = 0; k < 128; ++k) o += t1[k] * Wc2[k * 4 + f];
        out[b * 4 + f] = o;
    }
}

extern "C" void kernel_launch(void* const* d_in, const int* in_sizes, int n_in,
                              void* d_out, int out_size, void* d_ws, size_t ws_size,
                              hipStream_t stream) {
    const int* x      = (const int*)d_in[0];
    const int* ei     = (const int*)d_in[1];
    const float* ea   = (const float*)d_in[2];
    const int* batchh = (const int*)d_in[3];
    const float* emb  = (const float*)d_in[4];
    const float* Wm0 = (const float*)d_in[5];  const float* bm0 = (const float*)d_in[6];
    const float* We0 = (const float*)d_in[7];  const float* be0 = (const float*)d_in[8];
    const float* att0 = (const float*)d_in[9];
    const float* Ws0 = (const float*)d_in[10]; const float* bs0 = (const float*)d_in[11];
    const float* Wm1 = (const float*)d_in[12]; const float* bm1 = (const float*)d_in[13];
    const float* We1 = (const float*)d_in[14]; const float* be1 = (const float*)d_in[15];
    const float* att1 = (const float*)d_in[16];
    const float* Ws1 = (const float*)d_in[17]; const float* bs1 = (const float*)d_in[18];
    const float* Wc1 = (const float*)d_in[19]; const float* bc1 = (const float*)d_in[20];
    const float* Wc2 = (const float*)d_in[21]; const float* bc2 = (const float*)d_in[22];

    const int N = in_sizes[0];
    const int E = in_sizes[1] / 2;
    const int G = 64;
    const int H2 = 128;

    char* w = (char*)d_ws;
    auto alloc = [&](size_t bytes) -> void* {
        void* p = (void*)w;
        w += (bytes + 255) & ~(size_t)255;
        return p;
    };
    float* hbuf          = (float*)alloc((size_t)N * 128 * 4);
    unsigned char* hWm8  = (unsigned char*)alloc((size_t)N * 128);
    float* hWsb          = (float*)alloc((size_t)N * 128 * 4);
    float* nscore        = (float*)alloc((size_t)N * 4);
    float* escore        = (float*)alloc((size_t)E * 4);
    int* degcnt          = (int*)alloc((size_t)N * 4);
    int* csroff          = (int*)alloc((size_t)(N + 1) * 4);
    int* cursor          = (int*)alloc((size_t)N * 4);
    int* ce              = (int*)alloc((size_t)E * 4);
    float* watt          = (float*)alloc(16 * 4);
    float* gsum          = (float*)alloc((size_t)G * H2 * 4);
    int* gcnt            = (int*)alloc((size_t)G * 4);

    auto cdiv = [](int a, int b) { return (a + b - 1) / b; };

    hipMemsetAsync(degcnt, 0, (size_t)N * 4, stream);
    hipMemsetAsync(gsum, 0, (size_t)G * H2 * 4, stream);

    // CSR by dst
    count_kernel<<<cdiv(E, 256), 256, 0, stream>>>(ei, E, degcnt);
    scan_kernel<<<1, 1024, 0, stream>>>(degcnt, csroff, cursor, N);
    fill_kernel<<<cdiv(E, 256), 256, 0, stream>>>(ei, E, cursor, ce);

    // ---- layer 0: 64 -> 64 ----
    watt_kernel<<<1, 64, 0, stream>>>(We0, att0, be0, watt, 64);
    escore_kernel<<<cdiv(E, 256), 256, 0, stream>>>(ea, watt, escore, E);
    nodelin_kernel<64, 64><<<cdiv(N, 64), 256, 0, stream>>>(
        emb, x, Wm0, bm0, Ws0, bs0, att0, hWm8, hWsb, nscore, N);
    agg_kernel<64><<<N, 64, 0, stream>>>(csroff, ce, ei, E, nscore, escore, ea,
                                         We0, be0, hWm8, hWsb, hbuf, N);

    // ---- layer 1: 64 -> 128 ----
    watt_kernel<<<1, 64, 0, stream>>>(We1, att1, be1, watt, 128);
    escore_kernel<<<cdiv(E, 256), 256, 0, stream>>>(ea, watt, escore, E);
    nodelin_kernel<128, 32><<<cdiv(N, 32), 256, 0, stream>>>(
        hbuf, nullptr, Wm1, bm1, Ws1, bs1, att1, hWm8, hWsb, nscore, N);
    agg_kernel<128><<<N, 64, 0, stream>>>(csroff, ce, ei, E, nscore, escore, ea,
                                          We1, be1, hWm8, hWsb, hbuf, N);

    // ---- global mean pool + classifier ----
    graph_cnt_kernel<<<1, 64, 0, stream>>>(batchh, gcnt, N, G);
    pool_sum_kernel<<<512, 128, 0, stream>>>(hbuf, batchh, gsum, N);
    classifier_kernel<<<G, 128, 0, stream>>>(gsum, gcnt, Wc1, bc1, Wc2, bc2, (float*)d_out);
}

// Round 6
// 455.898 us; speedup vs baseline: 2.0636x; 1.1364x over previous
//
#include <hip/hip_runtime.h>
#include <hip/hip_bf16.h>

#define DEV_INLINE __device__ __forceinline__

static constexpr int WAVE = 64;
static constexpr float FP8_SCALE = 64.0f;
static constexpr float FP8_INV   = 1.0f / 64.0f;

DEV_INLINE float wave_max(float v) {
    #pragma unroll
    for (int o = 32; o > 0; o >>= 1) v = fmaxf(v, __shfl_xor(v, o));
    return v;
}
DEV_INLINE float wave_sum(float v) {
    #pragma unroll
    for (int o = 32; o > 0; o >>= 1) v += __shfl_xor(v, o);
    return v;
}
DEV_INLINE float leaky02(float x) { return x > 0.f ? x : 0.2f * x; }

// ---------------- CSR build ----------------
__global__ void count_kernel(const int* __restrict__ ei, int E, int* __restrict__ deg) {
    int i = blockIdx.x * blockDim.x + threadIdx.x;
    if (i >= E) return;
    atomicAdd(&deg[ei[E + i]], 1);
}

// Hierarchical scan, 1024-elem chunks: A) chunk sums  B) scan sums  C) final prefix.
__global__ __launch_bounds__(256)
void scan_partial_kernel(const int* __restrict__ deg, int* __restrict__ blocksum, int n) {
    int t = threadIdx.x;
    int base = blockIdx.x * 1024 + t * 4;
    int s = 0;
    #pragma unroll
    for (int j = 0; j < 4; ++j) { int i = base + j; if (i < n) s += deg[i]; }
    __shared__ int red[4];
    s = (int)wave_sum((float)s);  // exact: degrees < 2^24
    if ((t & 63) == 0) red[t >> 6] = s;
    __syncthreads();
    if (t == 0) blocksum[blockIdx.x] = red[0] + red[1] + red[2] + red[3];
}

__global__ __launch_bounds__(64)
void scan_blocksum_kernel(int* __restrict__ blocksum, int* __restrict__ off, int nblk, int n) {
    int lane = threadIdx.x;
    int v = (lane < nblk) ? blocksum[lane] : 0;
    int orig = v;
    #pragma unroll
    for (int o = 1; o < 64; o <<= 1) {
        int u = __shfl_up(v, o);
        if (lane >= o) v += u;
    }
    if (lane < nblk) blocksum[lane] = v - orig;  // exclusive
    if (lane == 63) off[n] = v;                  // grand total
}

__global__ __launch_bounds__(256)
void scan_final_kernel(const int* __restrict__ deg, const int* __restrict__ blockoff,
                       int* __restrict__ off, int* __restrict__ cursor, int n) {
    int t = threadIdx.x, lane = t & 63, wid = t >> 6;
    int base = blockIdx.x * 1024 + t * 4;
    int v[4], s = 0;
    #pragma unroll
    for (int j = 0; j < 4; ++j) {
        int i = base + j;
        v[j] = (i < n) ? deg[i] : 0;
        s += v[j];
    }
    int incl = s;
    #pragma unroll
    for (int o = 1; o < 64; o <<= 1) {
        int u = __shfl_up(incl, o);
        if (lane >= o) incl += u;
    }
    __shared__ int wtot[4];
    if (lane == 63) wtot[wid] = incl;
    __syncthreads();
    int woff = 0;
    for (int w0 = 0; w0 < wid; ++w0) woff += wtot[w0];
    int run = blockoff[blockIdx.x] + woff + incl - s;
    #pragma unroll
    for (int j = 0; j < 4; ++j) {
        int i = base + j;
        if (i < n) { off[i] = run; cursor[i] = run; }
        run += v[j];
    }
}

__global__ void fill_kernel(const int* __restrict__ ei, int E,
                            int* __restrict__ cursor, int* __restrict__ ce) {
    int i = blockIdx.x * blockDim.x + threadIdx.x;
    if (i >= E) return;
    int d = ei[E + i];
    int pos = atomicAdd(&cursor[d], 1);
    ce[pos] = i;
}

// ---------------- watt[k] = sum_h We[k,h]*att[h], watt[8] = be.att ----------------
__global__ void watt_kernel(const float* __restrict__ We, const float* __restrict__ att,
                            const float* __restrict__ be, float* __restrict__ watt, int H) {
    int lane = threadIdx.x;
    for (int k = 0; k < 8; ++k) {
        float s = 0.f;
        for (int h = lane; h < H; h += WAVE) s += We[k * H + h] * att[h];
        s = wave_sum(s);
        if (lane == 0) watt[k] = s;
    }
    float s = 0.f;
    for (int h = lane; h < H; h += WAVE) s += be[h] * att[h];
    s = wave_sum(s);
    if (lane == 0) watt[8] = s;
}

// ---------------- escore[e] = ea[e,:].watt + watt[8] ----------------
__global__ void escore_kernel(const float* __restrict__ ea, const float* __restrict__ watt,
                              float* __restrict__ escore, int E) {
    int e = blockIdx.x * blockDim.x + threadIdx.x;
    if (e >= E) return;
    const float4* p = reinterpret_cast<const float4*>(ea + (size_t)e * 8);
    float4 a0 = p[0], a1 = p[1];
    float s = watt[8];
    s += a0.x * watt[0] + a0.y * watt[1] + a0.z * watt[2] + a0.w * watt[3];
    s += a1.x * watt[4] + a1.y * watt[5] + a1.z * watt[6] + a1.w * watt[7];
    escore[e] = s;
}

// ---------------- node linear (LDS-tiled register-blocked GEMM) ----------------
// hWm8 (fp8 e4m3, x64 scale) = h@Wm+bm ; hWsb (fp32) = h@Ws+bs.
// Fused: nscore[row] = (h@Wm+bm).att (fp32, subgroup shfl_xor reduction).
// Optional xidx fuses emb[x] gather.
template <int H, int NB>
__global__ __launch_bounds__(256)
void nodelin_kernel(const float* __restrict__ h, const int* __restrict__ xidx,
                    const float* __restrict__ Wm, const float* __restrict__ bm,
                    const float* __restrict__ Ws, const float* __restrict__ bs,
                    const float* __restrict__ att,
                    unsigned char* __restrict__ hWm8, float* __restrict__ hWsb,
                    float* __restrict__ nscore, int n) {
    constexpr int F4  = H / 4;
    constexpr int NC  = 256 / F4;
    constexpr int NPT = NB / NC;
    constexpr int LDW = 68;
    __shared__ float sh[NB][LDW];
    int n0 = blockIdx.x * NB;
    int tid = threadIdx.x;

    for (int i = tid; i < NB * 16; i += 256) {
        int node = i >> 4, q = i & 15;
        int row = n0 + node;
        float4 v = make_float4(0.f, 0.f, 0.f, 0.f);
        if (row < n) {
            int src = xidx ? xidx[row] : row;
            v = reinterpret_cast<const float4*>(h + (size_t)src * 64)[q];
        }
        reinterpret_cast<float4*>(&sh[node][0])[q] = v;
    }
    __syncthreads();

    int f4 = (tid % F4) * 4;
    int j0 = tid / F4;
    float4 am[NPT], as[NPT];
    float4 bm4 = *reinterpret_cast<const float4*>(bm + f4);
    float4 bs4 = *reinterpret_cast<const float4*>(bs + f4);
    #pragma unroll
    for (int p = 0; p < NPT; ++p) { am[p] = bm4; as[p] = bs4; }

    for (int k4 = 0; k4 < 16; ++k4) {
        float4 hv[NPT];
        #pragma unroll
        for (int p = 0; p < NPT; ++p)
            hv[p] = reinterpret_cast<const float4*>(&sh[j0 + p * NC][0])[k4];
        #pragma unroll
        for (int kk = 0; kk < 4; ++kk) {
            int k = k4 * 4 + kk;
            float4 wm = *reinterpret_cast<const float4*>(Wm + k * H + f4);
            float4 ws = *reinterpret_cast<const float4*>(Ws + k * H + f4);
            #pragma unroll
            for (int p = 0; p < NPT; ++p) {
                float hk = (&hv[p].x)[kk];
                am[p].x += hk * wm.x; am[p].y += hk * wm.y;
                am[p].z += hk * wm.z; am[p].w += hk * wm.w;
                as[p].x += hk * ws.x; as[p].y += hk * ws.y;
                as[p].z += hk * ws.z; as[p].w += hk * ws.w;
            }
        }
    }

    float4 at4 = *reinterpret_cast<const float4*>(att + f4);
    #pragma unroll
    for (int p = 0; p < NPT; ++p) {
        int row = n0 + j0 + p * NC;
        float sc = am[p].x * at4.x + am[p].y * at4.y + am[p].z * at4.z + am[p].w * at4.w;
        #pragma unroll
        for (int o = 1; o < F4; o <<= 1) sc += __shfl_xor(sc, o);
        if (row < n) {
            int pk = 0;
            pk = __builtin_amdgcn_cvt_pk_fp8_f32(am[p].x * FP8_SCALE, am[p].y * FP8_SCALE, pk, false);
            pk = __builtin_amdgcn_cvt_pk_fp8_f32(am[p].z * FP8_SCALE, am[p].w * FP8_SCALE, pk, true);
            *reinterpret_cast<unsigned int*>(hWm8 + (size_t)row * H + f4) = (unsigned int)pk;
            *reinterpret_cast<float4*>(hWsb + (size_t)row * H + f4) = as[p];
            if ((tid % F4) == 0) nscore[row] = sc;
        }
    }
}

// ---------------- aggregation: fused softmax + weighted mean + skip + relu ----------------
template <int H>
__global__ __launch_bounds__(64)
void agg_kernel(const int* __restrict__ csr_off, const int* __restrict__ ce,
                const int* __restrict__ ei, int E,
                const float* __restrict__ nscore, const float* __restrict__ escore,
                const float* __restrict__ ea,
                const float* __restrict__ We, const float* __restrict__ be,
                const unsigned char* __restrict__ hWm8, const float* __restrict__ hWsb,
                float* __restrict__ hout, int n) {
    constexpr int R = H / 64;
    int node = blockIdx.x;
    if (node >= n) return;
    int lane = threadIdx.x;
    int off0 = csr_off[node];
    int deg = csr_off[node + 1] - off0;
    int fbase = lane * R;

    if (deg == 0) {
        #pragma unroll
        for (int r = 0; r < R; ++r) {
            float v = hWsb[(size_t)node * H + fbase + r];
            hout[(size_t)node * H + fbase + r] = fmaxf(v, 0.f);
        }
        return;
    }

    float cea[8];
    #pragma unroll
    for (int k = 0; k < 8; ++k) cea[k] = 0.f;
    float acc[R];
    #pragma unroll
    for (int r = 0; r < R; ++r) acc[r] = 0.f;

    if (deg <= WAVE) {
        int e = 0, s_ = 0;
        float a = -1e30f;
        if (lane < deg) {
            e = ce[off0 + lane];
            s_ = ei[e];
            a = leaky02(nscore[s_] + escore[e]);
        }
        float mx = wave_max(a);
        float cf = (lane < deg) ? expf(a - mx) : 0.f;
        float ssum = wave_sum(cf);
        cf *= 1.f / (ssum + 1e-16f);
        if (lane < deg) {
            const float4* p = reinterpret_cast<const float4*>(ea + (size_t)e * 8);
            float4 a0 = p[0], a1 = p[1];
            cea[0] = cf * a0.x; cea[1] = cf * a0.y; cea[2] = cf * a0.z; cea[3] = cf * a0.w;
            cea[4] = cf * a1.x; cea[5] = cf * a1.y; cea[6] = cf * a1.z; cea[7] = cf * a1.w;
        }
        #pragma unroll 4
        for (int j = 0; j < deg; ++j) {
            int sj = __shfl(s_, j);
            float cj = __shfl(cf, j);
            if constexpr (R == 2) {
                unsigned short u = *reinterpret_cast<const unsigned short*>(
                    hWm8 + (size_t)sj * H + 2 * lane);
                acc[0] += cj * __builtin_amdgcn_cvt_f32_fp8((int)u, 0);
                acc[1] += cj * __builtin_amdgcn_cvt_f32_fp8((int)u, 1);
            } else {
                unsigned char u = hWm8[(size_t)sj * H + lane];
                acc[0] += cj * __builtin_amdgcn_cvt_f32_fp8((int)u, 0);
            }
        }
    } else {
        float mx = -1e30f;
        for (int base = 0; base < deg; base += WAVE) {
            int i = base + lane;
            if (i < deg) {
                int e = ce[off0 + i];
                float a = leaky02(nscore[ei[e]] + escore[e]);
                mx = fmaxf(mx, a);
            }
        }
        mx = wave_max(mx);
        float ssum = 0.f;
        for (int base = 0; base < deg; base += WAVE) {
            int i = base + lane;
            if (i < deg) {
                int e = ce[off0 + i];
                float a = leaky02(nscore[ei[e]] + escore[e]);
                ssum += expf(a - mx);
            }
        }
        ssum = wave_sum(ssum);
        float invs = 1.f / (ssum + 1e-16f);
        for (int base = 0; base < deg; base += WAVE) {
            int cnt = min(WAVE, deg - base);
            int i = base + lane;
            int e = 0, s_ = 0;
            float cf = 0.f;
            if (i < deg) {
                e = ce[off0 + i];
                s_ = ei[e];
                float a = leaky02(nscore[s_] + escore[e]);
                cf = expf(a - mx) * invs;
                const float4* p = reinterpret_cast<const float4*>(ea + (size_t)e * 8);
                float4 a0 = p[0], a1 = p[1];
                cea[0] += cf * a0.x; cea[1] += cf * a0.y; cea[2] += cf * a0.z; cea[3] += cf * a0.w;
                cea[4] += cf * a1.x; cea[5] += cf * a1.y; cea[6] += cf * a1.z; cea[7] += cf * a1.w;
            }
            for (int j = 0; j < cnt; ++j) {
                int sj = __shfl(s_, j);
                float cj = __shfl(cf, j);
                if constexpr (R == 2) {
                    unsigned short u = *reinterpret_cast<const unsigned short*>(
                        hWm8 + (size_t)sj * H + 2 * lane);
                    acc[0] += cj * __builtin_amdgcn_cvt_f32_fp8((int)u, 0);
                    acc[1] += cj * __builtin_amdgcn_cvt_f32_fp8((int)u, 1);
                } else {
                    unsigned char u = hWm8[(size_t)sj * H + lane];
                    acc[0] += cj * __builtin_amdgcn_cvt_f32_fp8((int)u, 0);
                }
            }
        }
    }

    #pragma unroll
    for (int k = 0; k < 8; ++k) cea[k] = wave_sum(cea[k]);

    float invdeg = 1.f / (float)deg;
    #pragma unroll
    for (int r = 0; r < R; ++r) {
        float ew = be[fbase + r];
        #pragma unroll
        for (int k = 0; k < 8; ++k) ew += cea[k] * We[k * H + fbase + r];
        float v = (acc[r] * FP8_INV + ew) * invdeg + hWsb[(size_t)node * H + fbase + r];
        hout[(size_t)node * H + fbase + r] = fmaxf(v, 0.f);
    }
}

// ---------------- graph counts via binary search on sorted batchh ----------------
__global__ void graph_cnt_kernel(const int* __restrict__ batchh, int* __restrict__ gcnt,
                                 int n, int G) {
    int b = blockIdx.x * blockDim.x + threadIdx.x;
    if (b >= G) return;
    auto lb = [&](int key) {
        int lo = 0, hi = n;
        while (lo < hi) {
            int mid = (lo + hi) >> 1;
            if (batchh[mid] < key) lo = mid + 1; else hi = mid;
        }
        return lo;
    };
    gcnt[b] = lb(b + 1) - lb(b);
}

__global__ __launch_bounds__(128)
void pool_sum_kernel(const float* __restrict__ h, const int* __restrict__ batchh,
                     float* __restrict__ gsum, int n) {
    int f = threadIdx.x;
    int chunk = (n + gridDim.x - 1) / gridDim.x;
    int start = blockIdx.x * chunk;
    int end = min(n, start + chunk);
    if (start >= end) return;
    float acc = 0.f;
    int cur = batchh[start];
    for (int node = start; node < end; ++node) {
        int b = batchh[node];
        if (b != cur) {
            atomicAdd(&gsum[cur * 128 + f], acc);
            acc = 0.f;
            cur = b;
        }
        acc += h[(size_t)node * 128 + f];
    }
    atomicAdd(&gsum[cur * 128 + f], acc);
}

// ---------------- classifier ----------------
__global__ __launch_bounds__(128)
void classifier_kernel(const float* __restrict__ gsum, const int* __restrict__ gcnt,
                       const float* __restrict__ Wc1, const float* __restrict__ bc1,
                       const float* __restrict__ Wc2, const float* __restrict__ bc2,
                       float* __restrict__ out) {
    int b = blockIdx.x;
    int f = threadIdx.x;
    __shared__ float gm[128];
    __shared__ float t1[128];
    float c = (float)max(gcnt[b], 1);
    gm[f] = gsum[b * 128 + f] / c;
    __syncthreads();
    float acc = bc1[f];
    for (int k = 0; k < 128; ++k) acc += gm[k] * Wc1[k * 128 + f];
    t1[f] = fmaxf(acc, 0.f);
    __syncthreads();
    if (f < 4) {
        float o = bc2[f];
        for (int k = 0; k < 128; ++k) o += t1[k] * Wc2[k * 4 + f];
        out[b * 4 + f] = o;
    }
}

extern "C" void kernel_launch(void* const* d_in, const int* in_sizes, int n_in,
                              void* d_out, int out_size, void* d_ws, size_t ws_size,
                              hipStream_t stream) {
    const int* x      = (const int*)d_in[0];
    const int* ei     = (const int*)d_in[1];
    const float* ea   = (const float*)d_in[2];
    const int* batchh = (const int*)d_in[3];
    const float* emb  = (const float*)d_in[4];
    const float* Wm0 = (const float*)d_in[5];  const float* bm0 = (const float*)d_in[6];
    const float* We0 = (const float*)d_in[7];  const float* be0 = (const float*)d_in[8];
    const float* att0 = (const float*)d_in[9];
    const float* Ws0 = (const float*)d_in[10]; const float* bs0 = (const float*)d_in[11];
    const float* Wm1 = (const float*)d_in[12]; const float* bm1 = (const float*)d_in[13];
    const float* We1 = (const float*)d_in[14]; const float* be1 = (const float*)d_in[15];
    const float* att1 = (const float*)d_in[16];
    const float* Ws1 = (const float*)d_in[17]; const float* bs1 = (const float*)d_in[18];
    const float* Wc1 = (const float*)d_in[19]; const float* bc1 = (const float*)d_in[20];
    const float* Wc2 = (const float*)d_in[21]; const float* bc2 = (const float*)d_in[22];

    const int N = in_sizes[0];
    const int E = in_sizes[1] / 2;
    const int G = 64;
    const int H2 = 128;

    char* w = (char*)d_ws;
    auto alloc = [&](size_t bytes) -> void* {
        void* p = (void*)w;
        w += (bytes + 255) & ~(size_t)255;
        return p;
    };
    float* hbuf          = (float*)alloc((size_t)N * 128 * 4);
    unsigned char* hWm8  = (unsigned char*)alloc((size_t)N * 128);
    float* hWsb          = (float*)alloc((size_t)N * 128 * 4);
    float* nscore        = (float*)alloc((size_t)N * 4);
    float* escore        = (float*)alloc((size_t)E * 4);
    int* degcnt          = (int*)alloc((size_t)N * 4);
    int* csroff          = (int*)alloc((size_t)(N + 1) * 4);
    int* cursor          = (int*)alloc((size_t)N * 4);
    int* ce              = (int*)alloc((size_t)E * 4);
    float* watt          = (float*)alloc(16 * 4);
    float* gsum          = (float*)alloc((size_t)G * H2 * 4);
    int* gcnt            = (int*)alloc((size_t)G * 4);
    int* blocksum        = (int*)alloc(256 * 4);

    auto cdiv = [](int a, int b) { return (a + b - 1) / b; };
    const int NBLK = cdiv(N, 1024);

    hipMemsetAsync(degcnt, 0, (size_t)N * 4, stream);
    hipMemsetAsync(gsum, 0, (size_t)G * H2 * 4, stream);

    // CSR by dst (hierarchical scan)
    count_kernel<<<cdiv(E, 256), 256, 0, stream>>>(ei, E, degcnt);
    scan_partial_kernel<<<NBLK, 256, 0, stream>>>(degcnt, blocksum, N);
    scan_blocksum_kernel<<<1, 64, 0, stream>>>(blocksum, csroff, NBLK, N);
    scan_final_kernel<<<NBLK, 256, 0, stream>>>(degcnt, blocksum, csroff, cursor, N);
    fill_kernel<<<cdiv(E, 256), 256, 0, stream>>>(ei, E, cursor, ce);

    // ---- layer 0: 64 -> 64 ----
    watt_kernel<<<1, 64, 0, stream>>>(We0, att0, be0, watt, 64);
    escore_kernel<<<cdiv(E, 256), 256, 0, stream>>>(ea, watt, escore, E);
    nodelin_kernel<64, 64><<<cdiv(N, 64), 256, 0, stream>>>(
        emb, x, Wm0, bm0, Ws0, bs0, att0, hWm8, hWsb, nscore, N);
    agg_kernel<64><<<N, 64, 0, stream>>>(csroff, ce, ei, E, nscore, escore, ea,
                                         We0, be0, hWm8, hWsb, hbuf, N);

    // ---- layer 1: 64 -> 128 ----
    watt_kernel<<<1, 64, 0, stream>>>(We1, att1, be1, watt, 128);
    escore_kernel<<<cdiv(E, 256), 256, 0, stream>>>(ea, watt, escore, E);
    nodelin_kernel<128, 32><<<cdiv(N, 32), 256, 0, stream>>>(
        hbuf, nullptr, Wm1, bm1, Ws1, bs1, att1, hWm8, hWsb, nscore, N);
    agg_kernel<128><<<N, 64, 0, stream>>>(csroff, ce, ei, E, nscore, escore, ea,
                                          We1, be1, hWm8, hWsb, hbuf, N);

    // ---- global mean pool + classifier ----
    graph_cnt_kernel<<<1, 64, 0, stream>>>(batchh, gcnt, N, G);
    pool_sum_kernel<<<512, 128, 0, stream>>>(hbuf, batchh, gsum, N);
    classifier_kernel<<<G, 128, 0, stream>>>(gsum, gcnt, Wc1, bc1, Wc2, bc2, (float*)d_out);
}

// Round 7
// 420.293 us; speedup vs baseline: 2.2384x; 1.0847x over previous
//
#include <hip/hip_runtime.h>
#include <hip/hip_bf16.h>

#define DEV_INLINE __device__ __forceinline__

static constexpr int WAVE = 64;
static constexpr float FP8_SCALE = 64.0f;
static constexpr float FP8_INV   = 1.0f / 64.0f;

DEV_INLINE float wave_max(float v) {
    #pragma unroll
    for (int o = 32; o > 0; o >>= 1) v = fmaxf(v, __shfl_xor(v, o));
    return v;
}
DEV_INLINE float wave_sum(float v) {
    #pragma unroll
    for (int o = 32; o > 0; o >>= 1) v += __shfl_xor(v, o);
    return v;
}
DEV_INLINE float leaky02(float x) { return x > 0.f ? x : 0.2f * x; }
DEV_INLINE unsigned short f2b(float f) {
    __hip_bfloat16 b = __float2bfloat16(f);
    return *reinterpret_cast<unsigned short*>(&b);
}
DEV_INLINE float b2f(unsigned short u) {
    unsigned int x = ((unsigned int)u) << 16;
    return __uint_as_float(x);
}

// ---------------- CSR build ----------------
__global__ void count_kernel(const int* __restrict__ ei, int E, int* __restrict__ deg) {
    int i = blockIdx.x * blockDim.x + threadIdx.x;
    if (i >= E) return;
    atomicAdd(&deg[ei[E + i]], 1);
}

// Hierarchical scan, 1024-elem chunks.
__global__ __launch_bounds__(256)
void scan_partial_kernel(const int* __restrict__ deg, int* __restrict__ blocksum, int n) {
    int t = threadIdx.x;
    int base = blockIdx.x * 1024 + t * 4;
    int s = 0;
    #pragma unroll
    for (int j = 0; j < 4; ++j) { int i = base + j; if (i < n) s += deg[i]; }
    __shared__ int red[4];
    s = (int)wave_sum((float)s);
    if ((t & 63) == 0) red[t >> 6] = s;
    __syncthreads();
    if (t == 0) blocksum[blockIdx.x] = red[0] + red[1] + red[2] + red[3];
}

__global__ __launch_bounds__(64)
void scan_blocksum_kernel(int* __restrict__ blocksum, int* __restrict__ off, int nblk, int n) {
    int lane = threadIdx.x;
    int v = (lane < nblk) ? blocksum[lane] : 0;
    int orig = v;
    #pragma unroll
    for (int o = 1; o < 64; o <<= 1) {
        int u = __shfl_up(v, o);
        if (lane >= o) v += u;
    }
    if (lane < nblk) blocksum[lane] = v - orig;
    if (lane == 63) off[n] = v;
}

__global__ __launch_bounds__(256)
void scan_final_kernel(const int* __restrict__ deg, const int* __restrict__ blockoff,
                       int* __restrict__ off, int* __restrict__ cursor, int n) {
    int t = threadIdx.x, lane = t & 63, wid = t >> 6;
    int base = blockIdx.x * 1024 + t * 4;
    int v[4], s = 0;
    #pragma unroll
    for (int j = 0; j < 4; ++j) {
        int i = base + j;
        v[j] = (i < n) ? deg[i] : 0;
        s += v[j];
    }
    int incl = s;
    #pragma unroll
    for (int o = 1; o < 64; o <<= 1) {
        int u = __shfl_up(incl, o);
        if (lane >= o) incl += u;
    }
    __shared__ int wtot[4];
    if (lane == 63) wtot[wid] = incl;
    __syncthreads();
    int woff = 0;
    for (int w0 = 0; w0 < wid; ++w0) woff += wtot[w0];
    int run = blockoff[blockIdx.x] + woff + incl - s;
    #pragma unroll
    for (int j = 0; j < 4; ++j) {
        int i = base + j;
        if (i < n) { off[i] = run; cursor[i] = run; }
        run += v[j];
    }
}

__global__ void fill_kernel(const int* __restrict__ ei, int E,
                            int* __restrict__ cursor, int* __restrict__ ce) {
    int i = blockIdx.x * blockDim.x + threadIdx.x;
    if (i >= E) return;
    int d = ei[E + i];
    int pos = atomicAdd(&cursor[d], 1);
    ce[pos] = i;
}

// ---------------- watt[k] = sum_h We[k,h]*att[h], watt[8] = be.att ----------------
__global__ void watt_kernel(const float* __restrict__ We, const float* __restrict__ att,
                            const float* __restrict__ be, float* __restrict__ watt, int H) {
    int lane = threadIdx.x;
    for (int k = 0; k < 8; ++k) {
        float s = 0.f;
        for (int h = lane; h < H; h += WAVE) s += We[k * H + h] * att[h];
        s = wave_sum(s);
        if (lane == 0) watt[k] = s;
    }
    float s = 0.f;
    for (int h = lane; h < H; h += WAVE) s += be[h] * att[h];
    s = wave_sum(s);
    if (lane == 0) watt[8] = s;
}

// ---------------- escore[e] = ea[e,:].watt + watt[8] ----------------
__global__ void escore_kernel(const float* __restrict__ ea, const float* __restrict__ watt,
                              float* __restrict__ escore, int E) {
    int e = blockIdx.x * blockDim.x + threadIdx.x;
    if (e >= E) return;
    const float4* p = reinterpret_cast<const float4*>(ea + (size_t)e * 8);
    float4 a0 = p[0], a1 = p[1];
    float s = watt[8];
    s += a0.x * watt[0] + a0.y * watt[1] + a0.z * watt[2] + a0.w * watt[3];
    s += a1.x * watt[4] + a1.y * watt[5] + a1.z * watt[6] + a1.w * watt[7];
    escore[e] = s;
}

// ---------------- node linear (LDS-tiled register-blocked GEMM) ----------------
// hWm8 (fp8 e4m3, x64) = h@Wm+bm ; hWsb (bf16) = h@Ws+bs ; nscore (fp32) fused.
// INBF16: input activations are bf16 (layer 1). Else fp32 with optional xidx gather.
template <int H, int NB, bool INBF16>
__global__ __launch_bounds__(256)
void nodelin_kernel(const float* __restrict__ hf, const unsigned short* __restrict__ hb,
                    const int* __restrict__ xidx,
                    const float* __restrict__ Wm, const float* __restrict__ bm,
                    const float* __restrict__ Ws, const float* __restrict__ bs,
                    const float* __restrict__ att,
                    unsigned char* __restrict__ hWm8, unsigned short* __restrict__ hWsb,
                    float* __restrict__ nscore, int n) {
    constexpr int F4  = H / 4;
    constexpr int NC  = 256 / F4;
    constexpr int NPT = NB / NC;
    constexpr int LDW = 68;
    __shared__ float sh[NB][LDW];
    int n0 = blockIdx.x * NB;
    int tid = threadIdx.x;

    for (int i = tid; i < NB * 16; i += 256) {
        int node = i >> 4, q = i & 15;
        int row = n0 + node;
        float4 v = make_float4(0.f, 0.f, 0.f, 0.f);
        if (row < n) {
            if constexpr (INBF16) {
                ushort4 u = reinterpret_cast<const ushort4*>(hb + (size_t)row * 64)[q];
                v = make_float4(b2f(u.x), b2f(u.y), b2f(u.z), b2f(u.w));
            } else {
                int src = xidx ? xidx[row] : row;
                v = reinterpret_cast<const float4*>(hf + (size_t)src * 64)[q];
            }
        }
        reinterpret_cast<float4*>(&sh[node][0])[q] = v;
    }
    __syncthreads();

    int f4 = (tid % F4) * 4;
    int j0 = tid / F4;
    float4 am[NPT], as[NPT];
    float4 bm4 = *reinterpret_cast<const float4*>(bm + f4);
    float4 bs4 = *reinterpret_cast<const float4*>(bs + f4);
    #pragma unroll
    for (int p = 0; p < NPT; ++p) { am[p] = bm4; as[p] = bs4; }

    for (int k4 = 0; k4 < 16; ++k4) {
        float4 hv[NPT];
        #pragma unroll
        for (int p = 0; p < NPT; ++p)
            hv[p] = reinterpret_cast<const float4*>(&sh[j0 + p * NC][0])[k4];
        #pragma unroll
        for (int kk = 0; kk < 4; ++kk) {
            int k = k4 * 4 + kk;
            float4 wm = *reinterpret_cast<const float4*>(Wm + k * H + f4);
            float4 ws = *reinterpret_cast<const float4*>(Ws + k * H + f4);
            #pragma unroll
            for (int p = 0; p < NPT; ++p) {
                float hk = (&hv[p].x)[kk];
                am[p].x += hk * wm.x; am[p].y += hk * wm.y;
                am[p].z += hk * wm.z; am[p].w += hk * wm.w;
                as[p].x += hk * ws.x; as[p].y += hk * ws.y;
                as[p].z += hk * ws.z; as[p].w += hk * ws.w;
            }
        }
    }

    float4 at4 = *reinterpret_cast<const float4*>(att + f4);
    #pragma unroll
    for (int p = 0; p < NPT; ++p) {
        int row = n0 + j0 + p * NC;
        float sc = am[p].x * at4.x + am[p].y * at4.y + am[p].z * at4.z + am[p].w * at4.w;
        #pragma unroll
        for (int o = 1; o < F4; o <<= 1) sc += __shfl_xor(sc, o);
        if (row < n) {
            int pk = 0;
            pk = __builtin_amdgcn_cvt_pk_fp8_f32(am[p].x * FP8_SCALE, am[p].y * FP8_SCALE, pk, false);
            pk = __builtin_amdgcn_cvt_pk_fp8_f32(am[p].z * FP8_SCALE, am[p].w * FP8_SCALE, pk, true);
            *reinterpret_cast<unsigned int*>(hWm8 + (size_t)row * H + f4) = (unsigned int)pk;
            ushort4 sb;
            sb.x = f2b(as[p].x); sb.y = f2b(as[p].y); sb.z = f2b(as[p].z); sb.w = f2b(as[p].w);
            *reinterpret_cast<ushort4*>(hWsb + (size_t)row * H + f4) = sb;
            if ((tid % F4) == 0) nscore[row] = sc;
        }
    }
}

// ---------------- aggregation: fused softmax + weighted mean + skip + relu ----------------
// PE edges are gathered concurrently by 64/PE-lane subgroups (latency hiding);
// per-lane accumulators cover 4 features, merged by shfl_xor at the end.
template <int H>
__global__ __launch_bounds__(64)
void agg_kernel(const int* __restrict__ csr_off, const int* __restrict__ ce,
                const int* __restrict__ ei, int E,
                const float* __restrict__ nscore, const float* __restrict__ escore,
                const float* __restrict__ ea,
                const float* __restrict__ We, const float* __restrict__ be,
                const unsigned char* __restrict__ hWm8, const unsigned short* __restrict__ hWsb,
                unsigned short* __restrict__ hout, int n) {
    constexpr int PE   = (H == 128) ? 2 : 4;  // edges in flight
    constexpr int LSUB = 64 / PE;             // lanes per edge (cover H bytes as uints)
    int node = blockIdx.x;
    int lane = threadIdx.x;
    int sub = lane / LSUB;       // which edge of the group
    int fo  = lane % LSUB;       // uint offset in row; features 4*fo..4*fo+3
    int off0 = csr_off[node];
    int deg = csr_off[node + 1] - off0;

    if (deg == 0) {
        if (lane < LSUB) {
            ushort4 hs = *reinterpret_cast<const ushort4*>(hWsb + (size_t)node * H + 4 * fo);
            ushort4 ob;
            ob.x = f2b(fmaxf(b2f(hs.x), 0.f));
            ob.y = f2b(fmaxf(b2f(hs.y), 0.f));
            ob.z = f2b(fmaxf(b2f(hs.z), 0.f));
            ob.w = f2b(fmaxf(b2f(hs.w), 0.f));
            *reinterpret_cast<ushort4*>(hout + (size_t)node * H + 4 * fo) = ob;
        }
        return;
    }

    float cea[8];
    #pragma unroll
    for (int k = 0; k < 8; ++k) cea[k] = 0.f;
    float acc4[4] = {0.f, 0.f, 0.f, 0.f};

    auto accum_chunk = [&](int s_, float cf, int cnt) {
        for (int j0 = 0; j0 < cnt; j0 += PE) {
            int j = j0 + sub;
            int sj = __shfl(s_, j & 63);
            float cj = __shfl(cf, j & 63);
            if (j >= cnt) cj = 0.f;
            unsigned int g = *reinterpret_cast<const unsigned int*>(
                hWm8 + (size_t)sj * H + 4 * fo);
            acc4[0] += cj * __builtin_amdgcn_cvt_f32_fp8((int)g, 0);
            acc4[1] += cj * __builtin_amdgcn_cvt_f32_fp8((int)g, 1);
            acc4[2] += cj * __builtin_amdgcn_cvt_f32_fp8((int)g, 2);
            acc4[3] += cj * __builtin_amdgcn_cvt_f32_fp8((int)g, 3);
        }
    };

    if (deg <= WAVE) {
        int e = 0, s_ = 0;
        float a = -1e30f;
        if (lane < deg) {
            e = ce[off0 + lane];
            s_ = ei[e];
            a = leaky02(nscore[s_] + escore[e]);
        }
        float mx = wave_max(a);
        float cf = (lane < deg) ? expf(a - mx) : 0.f;
        float ssum = wave_sum(cf);
        cf *= 1.f / (ssum + 1e-16f);
        if (lane < deg) {
            const float4* p = reinterpret_cast<const float4*>(ea + (size_t)e * 8);
            float4 a0 = p[0], a1 = p[1];
            cea[0] = cf * a0.x; cea[1] = cf * a0.y; cea[2] = cf * a0.z; cea[3] = cf * a0.w;
            cea[4] = cf * a1.x; cea[5] = cf * a1.y; cea[6] = cf * a1.z; cea[7] = cf * a1.w;
        }
        accum_chunk(s_, cf, deg);
    } else {
        float mx = -1e30f;
        for (int base = 0; base < deg; base += WAVE) {
            int i = base + lane;
            if (i < deg) {
                int e = ce[off0 + i];
                float a = leaky02(nscore[ei[e]] + escore[e]);
                mx = fmaxf(mx, a);
            }
        }
        mx = wave_max(mx);
        float ssum = 0.f;
        for (int base = 0; base < deg; base += WAVE) {
            int i = base + lane;
            if (i < deg) {
                int e = ce[off0 + i];
                float a = leaky02(nscore[ei[e]] + escore[e]);
                ssum += expf(a - mx);
            }
        }
        ssum = wave_sum(ssum);
        float invs = 1.f / (ssum + 1e-16f);
        for (int base = 0; base < deg; base += WAVE) {
            int cnt = min(WAVE, deg - base);
            int i = base + lane;
            int e = 0, s_ = 0;
            float cf = 0.f;
            if (i < deg) {
                e = ce[off0 + i];
                s_ = ei[e];
                float a = leaky02(nscore[s_] + escore[e]);
                cf = expf(a - mx) * invs;
                const float4* p = reinterpret_cast<const float4*>(ea + (size_t)e * 8);
                float4 a0 = p[0], a1 = p[1];
                cea[0] += cf * a0.x; cea[1] += cf * a0.y; cea[2] += cf * a0.z; cea[3] += cf * a0.w;
                cea[4] += cf * a1.x; cea[5] += cf * a1.y; cea[6] += cf * a1.z; cea[7] += cf * a1.w;
            }
            accum_chunk(s_, cf, cnt);
        }
    }

    // merge edge-subgroup partial sums (features are replicated across subgroups)
    #pragma unroll
    for (int k = 0; k < 4; ++k) {
        if (PE == 4) acc4[k] += __shfl_xor(acc4[k], 16);
        acc4[k] += __shfl_xor(acc4[k], 32);
    }
    #pragma unroll
    for (int k = 0; k < 8; ++k) cea[k] = wave_sum(cea[k]);

    if (lane < LSUB) {
        float invdeg = 1.f / (float)deg;
        ushort4 hs = *reinterpret_cast<const ushort4*>(hWsb + (size_t)node * H + 4 * fo);
        float sk[4] = {b2f(hs.x), b2f(hs.y), b2f(hs.z), b2f(hs.w)};
        ushort4 ob;
        unsigned short* obp = &ob.x;
        #pragma unroll
        for (int k = 0; k < 4; ++k) {
            int f = 4 * fo + k;
            float ew = be[f];
            #pragma unroll
            for (int k8 = 0; k8 < 8; ++k8) ew += cea[k8] * We[k8 * H + f];
            float v = (acc4[k] * FP8_INV + ew) * invdeg + sk[k];
            obp[k] = f2b(fmaxf(v, 0.f));
        }
        *reinterpret_cast<ushort4*>(hout + (size_t)node * H + 4 * fo) = ob;
    }
}

// ---------------- graph counts via binary search on sorted batchh ----------------
__global__ void graph_cnt_kernel(const int* __restrict__ batchh, int* __restrict__ gcnt,
                                 int n, int G) {
    int b = blockIdx.x * blockDim.x + threadIdx.x;
    if (b >= G) return;
    auto lb = [&](int key) {
        int lo = 0, hi = n;
        while (lo < hi) {
            int mid = (lo + hi) >> 1;
            if (batchh[mid] < key) lo = mid + 1; else hi = mid;
        }
        return lo;
    };
    gcnt[b] = lb(b + 1) - lb(b);
}

__global__ __launch_bounds__(128)
void pool_sum_kernel(const unsigned short* __restrict__ h, const int* __restrict__ batchh,
                     float* __restrict__ gsum, int n) {
    int f = threadIdx.x;
    int chunk = (n + gridDim.x - 1) / gridDim.x;
    int start = blockIdx.x * chunk;
    int end = min(n, start + chunk);
    if (start >= end) return;
    float acc = 0.f;
    int cur = batchh[start];
    for (int node = start; node < end; ++node) {
        int b = batchh[node];
        if (b != cur) {
            atomicAdd(&gsum[cur * 128 + f], acc);
            acc = 0.f;
            cur = b;
        }
        acc += b2f(h[(size_t)node * 128 + f]);
    }
    atomicAdd(&gsum[cur * 128 + f], acc);
}

// ---------------- classifier ----------------
__global__ __launch_bounds__(128)
void classifier_kernel(const float* __restrict__ gsum, const int* __restrict__ gcnt,
                       const float* __restrict__ Wc1, const float* __restrict__ bc1,
                       const float* __restrict__ Wc2, const float* __restrict__ bc2,
                       float* __restrict__ out) {
    int b = blockIdx.x;
    int f = threadIdx.x;
    __shared__ float gm[128];
    __shared__ float t1[128];
    float c = (float)max(gcnt[b], 1);
    gm[f] = gsum[b * 128 + f] / c;
    __syncthreads();
    float acc = bc1[f];
    for (int k = 0; k < 128; ++k) acc += gm[k] * Wc1[k * 128 + f];
    t1[f] = fmaxf(acc, 0.f);
    __syncthreads();
    if (f < 4) {
        float o = bc2[f];
        for (int k = 0; k < 128; ++k) o += t1[k] * Wc2[k * 4 + f];
        out[b * 4 + f] = o;
    }
}

extern "C" void kernel_launch(void* const* d_in, const int* in_sizes, int n_in,
                              void* d_out, int out_size, void* d_ws, size_t ws_size,
                              hipStream_t stream) {
    const int* x      = (const int*)d_in[0];
    const int* ei     = (const int*)d_in[1];
    const float* ea   = (const float*)d_in[2];
    const int* batchh = (const int*)d_in[3];
    const float* emb  = (const float*)d_in[4];
    const float* Wm0 = (const float*)d_in[5];  const float* bm0 = (const float*)d_in[6];
    const float* We0 = (const float*)d_in[7];  const float* be0 = (const float*)d_in[8];
    const float* att0 = (const float*)d_in[9];
    const float* Ws0 = (const float*)d_in[10]; const float* bs0 = (const float*)d_in[11];
    const float* Wm1 = (const float*)d_in[12]; const float* bm1 = (const float*)d_in[13];
    const float* We1 = (const float*)d_in[14]; const float* be1 = (const float*)d_in[15];
    const float* att1 = (const float*)d_in[16];
    const float* Ws1 = (const float*)d_in[17]; const float* bs1 = (const float*)d_in[18];
    const float* Wc1 = (const float*)d_in[19]; const float* bc1 = (const float*)d_in[20];
    const float* Wc2 = (const float*)d_in[21]; const float* bc2 = (const float*)d_in[22];

    const int N = in_sizes[0];
    const int E = in_sizes[1] / 2;
    const int G = 64;
    const int H2 = 128;

    char* w = (char*)d_ws;
    auto alloc = [&](size_t bytes) -> void* {
        void* p = (void*)w;
        w += (bytes + 255) & ~(size_t)255;
        return p;
    };
    unsigned short* hbuf = (unsigned short*)alloc((size_t)N * 128 * 2);
    unsigned char* hWm8  = (unsigned char*)alloc((size_t)N * 128);
    unsigned short* hWsb = (unsigned short*)alloc((size_t)N * 128 * 2);
    float* nscore        = (float*)alloc((size_t)N * 4);
    float* escore        = (float*)alloc((size_t)E * 4);
    int* degcnt          = (int*)alloc((size_t)N * 4);
    int* csroff          = (int*)alloc((size_t)(N + 1) * 4);
    int* cursor          = (int*)alloc((size_t)N * 4);
    int* ce              = (int*)alloc((size_t)E * 4);
    float* watt          = (float*)alloc(16 * 4);
    float* gsum          = (float*)alloc((size_t)G * H2 * 4);
    int* gcnt            = (int*)alloc((size_t)G * 4);
    int* blocksum        = (int*)alloc(256 * 4);

    auto cdiv = [](int a, int b) { return (a + b - 1) / b; };
    const int NBLK = cdiv(N, 1024);

    hipMemsetAsync(degcnt, 0, (size_t)N * 4, stream);
    hipMemsetAsync(gsum, 0, (size_t)G * H2 * 4, stream);

    // CSR by dst (hierarchical scan)
    count_kernel<<<cdiv(E, 256), 256, 0, stream>>>(ei, E, degcnt);
    scan_partial_kernel<<<NBLK, 256, 0, stream>>>(degcnt, blocksum, N);
    scan_blocksum_kernel<<<1, 64, 0, stream>>>(blocksum, csroff, NBLK, N);
    scan_final_kernel<<<NBLK, 256, 0, stream>>>(degcnt, blocksum, csroff, cursor, N);
    fill_kernel<<<cdiv(E, 256), 256, 0, stream>>>(ei, E, cursor, ce);

    // ---- layer 0: 64 -> 64 ----
    watt_kernel<<<1, 64, 0, stream>>>(We0, att0, be0, watt, 64);
    escore_kernel<<<cdiv(E, 256), 256, 0, stream>>>(ea, watt, escore, E);
    nodelin_kernel<64, 64, false><<<cdiv(N, 64), 256, 0, stream>>>(
        emb, nullptr, x, Wm0, bm0, Ws0, bs0, att0, hWm8, hWsb, nscore, N);
    agg_kernel<64><<<N, 64, 0, stream>>>(csroff, ce, ei, E, nscore, escore, ea,
                                         We0, be0, hWm8, hWsb, hbuf, N);

    // ---- layer 1: 64 -> 128 ----
    watt_kernel<<<1, 64, 0, stream>>>(We1, att1, be1, watt, 128);
    escore_kernel<<<cdiv(E, 256), 256, 0, stream>>>(ea, watt, escore, E);
    nodelin_kernel<128, 32, true><<<cdiv(N, 32), 256, 0, stream>>>(
        nullptr, hbuf, nullptr, Wm1, bm1, Ws1, bs1, att1, hWm8, hWsb, nscore, N);
    agg_kernel<128><<<N, 64, 0, stream>>>(csroff, ce, ei, E, nscore, escore, ea,
                                          We1, be1, hWm8, hWsb, hbuf, N);

    // ---- global mean pool + classifier ----
    graph_cnt_kernel<<<1, 64, 0, stream>>>(batchh, gcnt, N, G);
    pool_sum_kernel<<<512, 128, 0, stream>>>(hbuf, batchh, gsum, N);
    classifier_kernel<<<G, 128, 0, stream>>>(gsum, gcnt, Wc1, bc1, Wc2, bc2, (float*)d_out);
}